// Round 7
// baseline (860.860 us; speedup 1.0000x reference)
//
#include <hip/hip_runtime.h>
#include <cmath>

typedef unsigned short u16;
typedef __attribute__((ext_vector_type(4))) float f32x4;
typedef __attribute__((ext_vector_type(4))) unsigned int u32x4;
typedef __attribute__((ext_vector_type(8))) __bf16 bf16x8;

__device__ __forceinline__ u16 f2b(float f) {
  unsigned int u = __builtin_bit_cast(unsigned int, f);
  return (u16)((u + 0x7fffu + ((u >> 16) & 1u)) >> 16);  // RNE
}
__device__ __forceinline__ float b2f(u16 h) {
  unsigned int u = ((unsigned int)h) << 16;
  return __builtin_bit_cast(float, u);
}

__device__ __forceinline__ void glds16(const u16* g, u16* l) {
  __builtin_amdgcn_global_load_lds(
      (const __attribute__((address_space(1))) void*)g,
      (__attribute__((address_space(3))) void*)l, 16, 0, 0);
}
__device__ __forceinline__ void nt16(u16* gdst, const u16* lsrc) {
  __builtin_nontemporal_store(*(const u32x4*)lsrc, (u32x4*)gdst);
}

// ---------------------------------------------------------------------------
// Fast bf16-MFMA GEMM, 128x128 tile, BK=32, 256 threads (4 waves, 2x2).
// A: M x K row-major bf16 (lda), per-z stride sA; B: N x K row-major (ldb).
// global_load_lds w16, double-buffered, counted vmcnt, chunk swizzle on both
// global-src and ds_read sides. Bijective XCD block remap (nwg % 8 == 0).
// All bulk epilogue stores: swizzled-LDS relayout -> full-line nontemporal.
// EPI 0: fused QKV (N=2304, cbuf=tileN/768): C row-major + C^T.
// EPI 1: TGSA reduce: v = sigmoid(acc+bias[n]) * tokb[m,n]; colsum/bsum/bsumsq
// EPI 2: store bf16 (acc*scale)  (attention scores; attN^T direct via operand
//        swap A=Kt,B=Qt)
// EPI 3: reduce-only: colsum[z,n], bsum[z], bsumsq[z]
// ---------------------------------------------------------------------------
template <int EPI>
__global__ __launch_bounds__(256) void gemm_f_k(
    const u16* __restrict__ Ap, const u16* __restrict__ Bp, u16* __restrict__ Cp,
    u16* __restrict__ CpT, const float* __restrict__ bias,
    const u16* __restrict__ tokp, float* __restrict__ colsum,
    float* __restrict__ bstat, int K, int lda, int ldb, int ldc, long sA,
    long sB, long sC, float scale) {
  __shared__ alignas(16) u16 smem[4][4096];  // A0,B0,A1,B1 : 128 rows x 32 u16
  __shared__ float scol_s[128];
  __shared__ float sred[2];

  // bijective XCD-chunked remap (nwg % 8 == 0 for all our grids)
  const int gx = gridDim.x, gxy = gx * gridDim.y;
  const int nwg = gxy * gridDim.z;
  int orig = (blockIdx.z * gridDim.y + blockIdx.y) * gx + blockIdx.x;
  int gwi = (orig & 7) * (nwg >> 3) + (orig >> 3);
  const int z = gwi / gxy;
  int rem = gwi - z * gxy;
  const int ty = rem / gx, tx = rem - ty * gx;
  const int tileM = ty << 7, tileN = tx << 7;

  const u16* Abase = Ap + (size_t)z * sA;
  const u16* Bbase = Bp + (size_t)z * sB;

  const int tid = threadIdx.x;
  const int lane = tid & 63, w = tid >> 6;
  const int wr = (w >> 1) << 6, wc = (w & 1) << 6;
  const int fr = lane & 15, fg = lane >> 4;

  f32x4 acc[4][4];
#pragma unroll
  for (int i = 0; i < 4; ++i)
#pragma unroll
    for (int j = 0; j < 4; ++j) acc[i][j] = (f32x4){0.f, 0.f, 0.f, 0.f};

  // staging: wave w covers rows [w*32, w*32+32); global col chunk pre-swizzled
  const int srow = (w << 5) + (lane >> 2);
  const int scol = (((lane & 3) ^ ((lane >> 3) & 3)) << 3);
  const u16* gA = Abase + (size_t)(tileM + srow) * lda + scol;
  const u16* gB = Bbase + (size_t)(tileN + srow) * ldb + scol;
  const int ldsw = (w << 5) * 32;  // u16 offset of wave's chunk

  auto STAGE = [&](int buf, int k0) {
    const u16* ga = gA + k0;
    const u16* gb = gB + k0;
    u16* la = &smem[buf * 2][ldsw];
    u16* lb = &smem[buf * 2 + 1][ldsw];
    glds16(ga, la);
    glds16(ga + (size_t)16 * lda, la + 512);
    glds16(gb, lb);
    glds16(gb + (size_t)16 * ldb, lb + 512);
  };

  // ds_read swizzle matches the pre-swizzled global source
  const int col_off = ((fg ^ ((fr >> 1) & 3)) << 3);

  const int nt = K >> 5;
  STAGE(0, 0);
  int cur = 0;
  for (int t = 0; t < nt; ++t) {
    if (t + 1 < nt) {
      STAGE(cur ^ 1, (t + 1) << 5);
      asm volatile("s_waitcnt vmcnt(4)" ::: "memory");
    } else {
      asm volatile("s_waitcnt vmcnt(0)" ::: "memory");
    }
    __builtin_amdgcn_s_barrier();
    asm volatile("" ::: "memory");
    const u16* Ab = smem[cur * 2];
    const u16* Bb = smem[cur * 2 + 1];
    bf16x8 av[4], bw[4];
#pragma unroll
    for (int m = 0; m < 4; ++m)
      av[m] = *(const bf16x8*)&Ab[(wr + (m << 4) + fr) * 32 + col_off];
#pragma unroll
    for (int n = 0; n < 4; ++n)
      bw[n] = *(const bf16x8*)&Bb[(wc + (n << 4) + fr) * 32 + col_off];
#pragma unroll
    for (int m = 0; m < 4; ++m)
#pragma unroll
      for (int n = 0; n < 4; ++n)
        acc[m][n] =
            __builtin_amdgcn_mfma_f32_16x16x32_bf16(av[m], bw[n], acc[m][n], 0, 0, 0);
    asm volatile("" ::: "memory");
    __builtin_amdgcn_s_barrier();
    cur ^= 1;
  }

  // ---- epilogue ----
  u16* tr = &smem[0][0];  // 128x128 u16 relayout tile (smem dead after K-loop)
  if constexpr (EPI == 0) {
    const int cbuf = tileN / 768;
    const int nbase = tileN - cbuf * 768;
    // pass 1: transposed tile -> Ct (full-line nt stores)
    const int xr = fr << 3;
#pragma unroll
    for (int m = 0; m < 4; ++m) {
#pragma unroll
      for (int n = 0; n < 4; ++n) {
        const int gcol = tileN + wc + (n << 4) + fr;
        const float bv2 = bias[gcol];
        union { u16 u[4]; unsigned long long q; } pk;
#pragma unroll
        for (int r = 0; r < 4; ++r) pk.u[r] = f2b(acc[m][n][r] + bv2);
        const int rowb = wr + (m << 4) + (fg << 2);
        *(unsigned long long*)&tr[(wc + (n << 4) + fr) * 128 + (rowb ^ xr)] = pk.q;
      }
    }
    __syncthreads();
    {
      u16* Ct = CpT + (size_t)cbuf * sC;
      const int col = tid >> 1, rh = (tid & 1) << 6;
      const int xc = (col & 15) << 3;
      const u16* trc = &tr[col * 128];
      u16* outc = &Ct[(size_t)(nbase + col) * 16384 + tileM];
#pragma unroll
      for (int i = 0; i < 8; ++i) {
        const int r0 = rh + (i << 3);
        nt16(&outc[r0], &trc[r0 ^ xc]);
      }
    }
    __syncthreads();
    // pass 2: row-major tile -> Cz (full-line nt stores)
#pragma unroll
    for (int m = 0; m < 4; ++m) {
#pragma unroll
      for (int n = 0; n < 4; ++n) {
        const int col = wc + (n << 4) + fr;
        const float bv2 = bias[tileN + col];
#pragma unroll
        for (int r = 0; r < 4; ++r) {
          const int row = wr + (m << 4) + (fg << 2) + r;
          tr[row * 128 + (col ^ ((row & 7) << 4))] = f2b(acc[m][n][r] + bv2);
        }
      }
    }
    __syncthreads();
    {
      u16* Cz = Cp + (size_t)cbuf * sC;
      const int row = tid >> 1, cb = (tid & 1) << 6;
      const int x = (row & 7) << 4;
      const u16* src = &tr[row * 128];
      u16* dst = &Cz[(size_t)(tileM + row) * 768 + nbase + cb];
#pragma unroll
      for (int a = 0; a < 8; ++a) nt16(&dst[a << 3], &src[(cb + (a << 3)) ^ x]);
    }
  } else if constexpr (EPI == 1) {
    // TGSA: v = sigmoid(acc + btg[n]) * tokb[m,n]
    if (tid < 128) scol_s[tid] = 0.f;
    if (tid == 0) { sred[0] = 0.f; sred[1] = 0.f; }
    __syncthreads();
    float ls = 0.f, lq = 0.f;
#pragma unroll
    for (int n = 0; n < 4; ++n) {
      float cpart = 0.f;
      const int gcol = tileN + wc + (n << 4) + fr;
      const float bv2 = bias[gcol];
#pragma unroll
      for (int m = 0; m < 4; ++m) {
#pragma unroll
        for (int r = 0; r < 4; ++r) {
          const int grow = tileM + wr + (m << 4) + (fg << 2) + r;
          float g = 1.f / (1.f + __expf(-(acc[m][n][r] + bv2)));
          float v = g * b2f(tokp[(size_t)grow * 768 + gcol]);
          cpart += v; ls += v; lq += v * v;
        }
      }
      atomicAdd(&scol_s[wc + (n << 4) + fr], cpart);
    }
    atomicAdd(&sred[0], ls);
    atomicAdd(&sred[1], lq);
    __syncthreads();
    const int b = tileM >> 9;
    if (tid < 128) atomicAdd(&colsum[(size_t)b * 768 + tileN + tid], scol_s[tid]);
    if (tid == 0) {
      atomicAdd(&bstat[b], sred[0]);
      atomicAdd(&bstat[32 + b], sred[1]);
    }
  } else if constexpr (EPI == 2) {
    // scores: row-major store through swizzled LDS, full-line nt
#pragma unroll
    for (int m = 0; m < 4; ++m) {
#pragma unroll
      for (int n = 0; n < 4; ++n) {
        const int col = wc + (n << 4) + fr;
#pragma unroll
        for (int r = 0; r < 4; ++r) {
          const int row = wr + (m << 4) + (fg << 2) + r;
          tr[row * 128 + (col ^ ((row & 7) << 4))] = f2b(acc[m][n][r] * scale);
        }
      }
    }
    __syncthreads();
    u16* Cz = Cp + (size_t)z * sC;
    const int row = tid >> 1, cb = (tid & 1) << 6;
    const int x = (row & 7) << 4;
    const u16* src = &tr[row * 128];
    u16* dst = &Cz[(size_t)(tileM + row) * ldc + tileN + cb];
#pragma unroll
    for (int a = 0; a < 8; ++a) nt16(&dst[a << 3], &src[(cb + (a << 3)) ^ x]);
  } else {
    if (tid < 128) scol_s[tid] = 0.f;
    if (tid == 0) { sred[0] = 0.f; sred[1] = 0.f; }
    __syncthreads();
    float ls = 0.f, lq = 0.f;
#pragma unroll
    for (int n = 0; n < 4; ++n) {
      float cpart = 0.f;
#pragma unroll
      for (int m = 0; m < 4; ++m) {
#pragma unroll
        for (int r = 0; r < 4; ++r) {
          float v = acc[m][n][r];
          cpart += v; ls += v; lq += v * v;
        }
      }
      atomicAdd(&scol_s[wc + (n << 4) + fr], cpart);
    }
    atomicAdd(&sred[0], ls);
    atomicAdd(&sred[1], lq);
    __syncthreads();
    if (tid < 128) atomicAdd(&colsum[(size_t)z * 768 + tileN + tid], scol_s[tid]);
    if (tid == 0) {
      atomicAdd(&bstat[z], sred[0]);
      atomicAdd(&bstat[32 + z], sred[1]);
    }
  }
}

// fused: tokens f32 -> tokb bf16 + per-row gate_t/rowsum/rowsumsq. 1 wave/row.
__global__ __launch_bounds__(256) void cvt_row_k(
    const float* __restrict__ tok, u16* __restrict__ tokb,
    const float* __restrict__ Wts, const float* __restrict__ bts,
    float* __restrict__ gate_t, float* __restrict__ rowsum,
    float* __restrict__ rowsumsq) {
  const int w = threadIdx.x >> 6, lane = threadIdx.x & 63;
  const int row = blockIdx.x * 4 + w;
  const float* p = tok + (size_t)row * 768;
  u16* q = tokb + (size_t)row * 768;
  float s = 0.f, sq = 0.f, g = 0.f;
#pragma unroll
  for (int i = 0; i < 3; ++i) {
    const int idx = (i * 64 + lane) << 2;
    f32x4 v = *(const f32x4*)(p + idx);
    f32x4 wv = *(const f32x4*)(Wts + idx);
    union { u16 u[4]; unsigned long long q8; } pk;
#pragma unroll
    for (int j = 0; j < 4; ++j) {
      s += v[j]; sq += v[j] * v[j]; g += v[j] * wv[j];
      pk.u[j] = f2b(v[j]);
    }
    *(unsigned long long*)(q + idx) = pk.q8;
  }
#pragma unroll
  for (int o = 32; o > 0; o >>= 1) {
    s += __shfl_xor(s, o); sq += __shfl_xor(sq, o); g += __shfl_xor(g, o);
  }
  if (lane == 0) {
    gate_t[row] = fmaxf(g + bts[0], 0.f);
    rowsum[row] = s;
    rowsumsq[row] = sq;
  }
}

// W [768][768] f32 -> WT [768][768] bf16 (transposed)
__global__ __launch_bounds__(256) void transpose_w_k(const float* __restrict__ W,
                                                     u16* __restrict__ WT) {
  __shared__ float t[64][65];
  const int r0 = blockIdx.y << 6, c0 = blockIdx.x << 6;
  for (int i = threadIdx.x; i < 4096; i += 256) {
    int r = i >> 6, c = i & 63;
    t[r][c] = W[(size_t)(r0 + r) * 768 + c0 + c];
  }
  __syncthreads();
  for (int i = threadIdx.x; i < 4096; i += 256) {
    int rr = i >> 6, cc = i & 63;
    WT[(size_t)(c0 + rr) * 768 + r0 + cc] = f2b(t[cc][rr]);
  }
}

// in-place row softmax on bf16 scores; block=256, grid=numRows
template <int LEN>
__global__ __launch_bounds__(256) void softmax_k(u16* __restrict__ data) {
  constexpr int NP = LEN / 256;
  const int row = blockIdx.x, tid = threadIdx.x;
  u16* p = data + (size_t)row * LEN;
  const int lane = tid & 63, wid = tid >> 6;
  float v[NP];
  float mx = -1e30f;
#pragma unroll
  for (int i = 0; i < NP; ++i) { v[i] = b2f(p[tid + (i << 8)]); mx = fmaxf(mx, v[i]); }
#pragma unroll
  for (int o = 32; o > 0; o >>= 1) mx = fmaxf(mx, __shfl_xor(mx, o));
  __shared__ float red[4], red2[4];
  if (lane == 0) red[wid] = mx;
  __syncthreads();
  mx = fmaxf(fmaxf(red[0], red[1]), fmaxf(red[2], red[3]));
  float sum = 0.f;
#pragma unroll
  for (int i = 0; i < NP; ++i) { v[i] = __expf(v[i] - mx); sum += v[i]; }
#pragma unroll
  for (int o = 32; o > 0; o >>= 1) sum += __shfl_xor(sum, o);
  if (lane == 0) red2[wid] = sum;
  __syncthreads();
  sum = red2[0] + red2[1] + red2[2] + red2[3];
  const float inv = 1.f / sum;
#pragma unroll
  for (int i = 0; i < NP; ++i) p[tid + (i << 8)] = f2b(v[i] * inv);
}

// column softmax on attNt [32][768(g)][768(h)]: softmax over g per (b,h).
// grid (32, 12), 256 thr: 64 h-columns x 4 g-stripes, LDS-combined max/sum.
__global__ __launch_bounds__(256) void colsoftmax_k(u16* __restrict__ data) {
  const int b = blockIdx.x;
  const int l = threadIdx.x & 63, st = threadIdx.x >> 6;
  const int h = (blockIdx.y << 6) + l;
  u16* p = data + (size_t)b * 589824 + h;
  const int g0 = st * 192;
  float m = -1e30f, s = 0.f;
#pragma unroll 4
  for (int g = g0; g < g0 + 192; ++g) {
    float v = b2f(p[(size_t)g * 768]);
    float mn = fmaxf(m, v);
    s = s * __expf(m - mn) + __expf(v - mn);
    m = mn;
  }
  __shared__ float sm[4][64], ss[4][64];
  sm[st][l] = m; ss[st][l] = s;
  __syncthreads();
  const float M = fmaxf(fmaxf(sm[0][l], sm[1][l]), fmaxf(sm[2][l], sm[3][l]));
  const float S = ss[0][l] * __expf(sm[0][l] - M) + ss[1][l] * __expf(sm[1][l] - M) +
                  ss[2][l] * __expf(sm[2][l] - M) + ss[3][l] * __expf(sm[3][l] - M);
  const float inv = 1.f / S;
#pragma unroll 4
  for (int g = g0; g < g0 + 192; ++g) {
    float v = b2f(p[(size_t)g * 768]);
    p[(size_t)g * 768] = f2b(__expf(v - M) * inv);
  }
}

// per-column stats from tokb: gate_f, colsum_tok, colsumsq_tok, colsum_tsgsa.
__global__ __launch_bounds__(256) void col_stats_k(
    const u16* __restrict__ tokb, const float* __restrict__ Wfs,
    const float* __restrict__ bfs, const float* __restrict__ gate_t,
    float* __restrict__ gate_f, float* __restrict__ colsum_tok,
    float* __restrict__ colsumsq_tok, float* __restrict__ colsum_tsg) {
  const int b = blockIdx.x, h = blockIdx.y * 256 + threadIdx.x;
  const u16* p = tokb + (size_t)b * 512 * 768 + h;
  const float* gt = gate_t + b * 512;
  float cs = 0.f, cq = 0.f, gf = 0.f, tg = 0.f;
#pragma unroll 4
  for (int s = 0; s < 512; ++s) {
    float t = b2f(p[(size_t)s * 768]);
    cs += t; cq += t * t; gf += t * Wfs[s]; tg += t * gt[s];
  }
  const int idx = b * 768 + h;
  gate_f[idx] = fmaxf(gf + bfs[0], 0.f);
  colsum_tok[idx] = cs;
  colsumsq_tok[idx] = cq;
  colsum_tsg[idx] = tg;
}

// per-batch scalar stats for TSGSA and FSGSA. st: [tsg_s|tsg_q|fsg_s|fsg_q]x32
__global__ __launch_bounds__(256) void batch_stats_k(
    const float* __restrict__ gate_t, const float* __restrict__ rowsum,
    const float* __restrict__ rowsumsq, const float* __restrict__ gate_f,
    const float* __restrict__ colsum_tok, const float* __restrict__ colsumsq_tok,
    float* __restrict__ st) {
  __shared__ float red[4][256];
  const int b = blockIdx.x, tid = threadIdx.x;
  float ts = 0.f, tq = 0.f, fs = 0.f, fq = 0.f;
  for (int s = tid; s < 512; s += 256) {
    float g = gate_t[b * 512 + s];
    ts += g * rowsum[b * 512 + s];
    tq += g * g * rowsumsq[b * 512 + s];
  }
  for (int h = tid; h < 768; h += 256) {
    float g = gate_f[b * 768 + h];
    fs += g * colsum_tok[b * 768 + h];
    fq += g * g * colsumsq_tok[b * 768 + h];
  }
  red[0][tid] = ts; red[1][tid] = tq; red[2][tid] = fs; red[3][tid] = fq;
  __syncthreads();
  for (int o = 128; o > 0; o >>= 1) {
    if (tid < o) {
      red[0][tid] += red[0][tid + o];
      red[1][tid] += red[1][tid + o];
      red[2][tid] += red[2][tid + o];
      red[3][tid] += red[3][tid + o];
    }
    __syncthreads();
  }
  if (tid == 0) {
    st[b] = red[0][0]; st[32 + b] = red[1][0];
    st[64 + b] = red[2][0]; st[96 + b] = red[3][0];
  }
}

// build pooled [B, 7*768] from column sums + batch stats
__global__ __launch_bounds__(768) void pooled_k(
    const float* __restrict__ colsum_tok, const float* __restrict__ colsum_tsa,
    const float* __restrict__ bstat_tsa, const float* __restrict__ colsum_fsa,
    const float* __restrict__ bstat_fsa, const float* __restrict__ colsum_tgsa,
    const float* __restrict__ bstat_tgsa, const float* __restrict__ colsum_tsg,
    const float* __restrict__ gate_f, const float* __restrict__ st,
    float* __restrict__ pooled) {
  const int b = blockIdx.x, h = threadIdx.x;
  const float invS = 1.f / 512.f, invN = 1.f / (512.f * 768.f);
  const int i = b * 768 + h;
  float* pr = pooled + (size_t)b * 5376;
  pr[h] = colsum_tok[i] * invS;
  auto lnslot = [&](int slot, float cs, float bs, float bq) {
    float m = bs * invN;
    float var = bq * invN - m * m;
    pr[slot * 768 + h] = (cs * invS - m) * rsqrtf(var + 1e-8f);
  };
  lnslot(1, colsum_tsa[i], bstat_tsa[b], bstat_tsa[32 + b]);
  lnslot(2, colsum_fsa[i], bstat_fsa[b], bstat_fsa[32 + b]);
  lnslot(3, colsum_tgsa[i], bstat_tgsa[b], bstat_tgsa[32 + b]);
  const float fsg_cs = gate_f[i] * colsum_tok[i];
  lnslot(4, fsg_cs, st[64 + b], st[96 + b]);
  lnslot(5, colsum_tsg[i], st[b], st[32 + b]);
  lnslot(6, fsg_cs, st[64 + b], st[96 + b]);
}

// tmp1 += pooled-slice . W1-slice.  grid (6 colchunks, 42 kchunks), 256 thr.
__global__ __launch_bounds__(256) void fnn1_k(const float* __restrict__ pooled,
                                              const float* __restrict__ W1,
                                              float* __restrict__ tmp1) {
  __shared__ float sp[128][36];
  const int c0 = blockIdx.x << 7, k0 = blockIdx.y << 7;
  const int tid = threadIdx.x;
  for (int i = tid; i < 4096; i += 256) {
    int b = i >> 7, j = i & 127;
    sp[j][b] = pooled[(size_t)b * 5376 + k0 + j];
  }
  __syncthreads();
  const int c = c0 + (tid & 127);
  const int u = (tid >> 7) << 4;
  float acc[16];
#pragma unroll
  for (int t = 0; t < 16; ++t) acc[t] = 0.f;
#pragma unroll 4
  for (int j = 0; j < 128; ++j) {
    float w = W1[(size_t)(k0 + j) * 768 + c];
    const f32x4* row = (const f32x4*)&sp[j][u];
#pragma unroll
    for (int t4 = 0; t4 < 4; ++t4) {
      f32x4 v = row[t4];
#pragma unroll
      for (int r = 0; r < 4; ++r) acc[t4 * 4 + r] += v[r] * w;
    }
  }
#pragma unroll
  for (int t = 0; t < 16; ++t) atomicAdd(&tmp1[(u + t) * 768 + c], acc[t]);
}

// out[b,c] = sum_k (tmp1[b,k]+b1[k]) * W2[k,c] + b2[c].  One wave per output.
__global__ __launch_bounds__(256) void fnn2_k(const float* __restrict__ tmp1,
                                              const float* __restrict__ b1,
                                              const float* __restrict__ W2,
                                              const float* __restrict__ b2,
                                              float* __restrict__ out) {
  const int gw = blockIdx.x * 4 + (threadIdx.x >> 6);
  const int lane = threadIdx.x & 63;
  const int b = gw / 3, c = gw % 3;
  float a = 0.f;
#pragma unroll
  for (int i = 0; i < 12; ++i) {
    int k = lane + i * 64;
    a += (tmp1[b * 768 + k] + b1[k]) * W2[k * 3 + c];
  }
#pragma unroll
  for (int o = 32; o > 0; o >>= 1) a += __shfl_xor(a, o);
  if (lane == 0) out[b * 3 + c] = a + b2[c];
}

extern "C" void kernel_launch(void* const* d_in, const int* in_sizes, int n_in,
                              void* d_out, int out_size, void* d_ws, size_t ws_size,
                              hipStream_t stream) {
  const float* tokens = (const float*)d_in[0];
  const float* Wq = (const float*)d_in[1];
  const float* bq = (const float*)d_in[2];
  const float* Wk = (const float*)d_in[3];
  const float* bk = (const float*)d_in[4];
  const float* Wv = (const float*)d_in[5];
  const float* bv = (const float*)d_in[6];
  const float* Wts = (const float*)d_in[7];
  const float* bts = (const float*)d_in[8];
  const float* Wfs = (const float*)d_in[9];
  const float* bfs = (const float*)d_in[10];
  const float* Wtg = (const float*)d_in[11];
  const float* btg = (const float*)d_in[12];
  const float* W1 = (const float*)d_in[13];
  const float* b1 = (const float*)d_in[14];
  const float* W2 = (const float*)d_in[15];
  const float* b2 = (const float*)d_in[16];
  float* out = (float*)d_out;

  char* ws = (char*)d_ws;
  size_t off = 0;
  auto take = [&](size_t bytes) -> char* {
    char* p = ws + off;
    off += (bytes + 255) & ~(size_t)255;
    return p;
  };
  u16* tokb = (u16*)take((size_t)16384 * 768 * 2);
  u16* WqT = (u16*)take((size_t)768 * 768 * 2);  // WqT/WkT/WvT contiguous
  u16* WkT = (u16*)take((size_t)768 * 768 * 2);
  u16* WvT = (u16*)take((size_t)768 * 768 * 2);
  u16* WtgT = (u16*)take((size_t)768 * 768 * 2);
  u16* Qb = (u16*)take((size_t)16384 * 768 * 2);  // Qb/Kb/Vb contiguous
  u16* Kb = (u16*)take((size_t)16384 * 768 * 2);
  u16* Vb = (u16*)take((size_t)16384 * 768 * 2);
  u16* Qt = (u16*)take((size_t)768 * 16384 * 2);  // Qt/Kt/Vt contiguous
  u16* Kt = (u16*)take((size_t)768 * 16384 * 2);
  u16* Vt = (u16*)take((size_t)768 * 16384 * 2);
  u16* attb = (u16*)take((size_t)32 * 512 * 512 * 2);
  u16* attNt = (u16*)take((size_t)32 * 768 * 768 * 2);  // attN^T [b][g][h]
  float* bias3 = (float*)take(2304 * 4);
  // --- zeroed (atomic-accumulated) region: keep contiguous ---
  char* zbase = ws + off;
  float* colsum_tsa = (float*)take(24576 * 4);
  float* colsum_fsa = (float*)take(24576 * 4);
  float* colsum_tgsa = (float*)take(24576 * 4);
  float* bstat_tsa = (float*)take(64 * 4);
  float* bstat_fsa = (float*)take(64 * 4);
  float* bstat_tgsa = (float*)take(64 * 4);
  float* tmp1 = (float*)take((size_t)32 * 768 * 4);
  size_t zbytes = (size_t)((ws + off) - zbase);
  // --- fully-overwritten buffers ---
  float* colsum_tsg = (float*)take(24576 * 4);
  float* gate_t = (float*)take(16384 * 4);
  float* rowsum = (float*)take(16384 * 4);
  float* rowsumsq = (float*)take(16384 * 4);
  float* gate_f = (float*)take(24576 * 4);
  float* colsum_tok = (float*)take(24576 * 4);
  float* colsumsq_tok = (float*)take(24576 * 4);
  float* st4 = (float*)take(128 * 4);
  float* pooled = (float*)take((size_t)32 * 5376 * 4);

  hipMemsetAsync(zbase, 0, zbytes, stream);
  hipMemcpyAsync(bias3, bq, 768 * 4, hipMemcpyDeviceToDevice, stream);
  hipMemcpyAsync(bias3 + 768, bk, 768 * 4, hipMemcpyDeviceToDevice, stream);
  hipMemcpyAsync(bias3 + 1536, bv, 768 * 4, hipMemcpyDeviceToDevice, stream);

  const float scale = 1.0f / sqrtf(768.0f);
  const dim3 blk(256);

  // prep: tokens->bf16 + row stats (fused); weights->transposed bf16
  cvt_row_k<<<4096, blk, 0, stream>>>(tokens, tokb, Wts, bts, gate_t, rowsum,
                                      rowsumsq);
  transpose_w_k<<<dim3(12, 12), blk, 0, stream>>>(Wq, WqT);
  transpose_w_k<<<dim3(12, 12), blk, 0, stream>>>(Wk, WkT);
  transpose_w_k<<<dim3(12, 12), blk, 0, stream>>>(Wv, WvT);
  transpose_w_k<<<dim3(12, 12), blk, 0, stream>>>(Wtg, WtgT);

  // fused Q|K|V projection: N=2304 (B panel 3.5MB fits per-XCD L2)
  gemm_f_k<0><<<dim3(18, 128, 1), blk, 0, stream>>>(
      tokb, WqT, Qb, Qt, bias3, nullptr, nullptr, nullptr, 768, 768, 768, 768,
      0, 0, 12582912, 0.f);
  // TGSA (gated reduce), separate dispatch
  gemm_f_k<1><<<dim3(6, 128, 1), blk, 0, stream>>>(
      tokb, WtgT, nullptr, nullptr, btg, tokb, colsum_tgsa, bstat_tgsa, 768,
      768, 768, 0, 0, 0, 0, 0.f);

  // attN^T directly: attNt[g][h] = sum_s Kt[g][s] Qt[h][s]  (operand swap)
  gemm_f_k<2><<<dim3(6, 6, 32), blk, 0, stream>>>(
      Kt, Qt, attNt, nullptr, nullptr, nullptr, nullptr, nullptr, 512, 16384,
      16384, 768, 512, 512, 589824, scale);
  colsoftmax_k<<<dim3(32, 12), blk, 0, stream>>>(attNt);

  // token attention scores: att[s,t] = Q[s,:].K[t,:] * scale
  gemm_f_k<2><<<dim3(4, 4, 32), blk, 0, stream>>>(
      Qb, Kb, attb, nullptr, nullptr, nullptr, nullptr, nullptr, 768, 768, 768,
      512, 393216, 393216, 262144, scale);
  softmax_k<512><<<16384, 256, 0, stream>>>(attb);

  // TSA = att @ V  -> reduce only
  gemm_f_k<3><<<dim3(6, 4, 32), blk, 0, stream>>>(
      attb, Vt, nullptr, nullptr, nullptr, nullptr, colsum_tsa, bstat_tsa, 512,
      512, 16384, 0, 262144, 512, 0, 0.f);
  // FSA = V @ attN -> reduce only  (B rows = attNt rows g)
  gemm_f_k<3><<<dim3(6, 4, 32), blk, 0, stream>>>(
      Vb, attNt, nullptr, nullptr, nullptr, nullptr, colsum_fsa, bstat_fsa, 768,
      768, 768, 0, 393216, 589824, 0, 0.f);

  // remaining gate-branch statistics
  col_stats_k<<<dim3(32, 3), blk, 0, stream>>>(tokb, Wfs, bfs, gate_t, gate_f,
                                               colsum_tok, colsumsq_tok, colsum_tsg);
  batch_stats_k<<<32, blk, 0, stream>>>(gate_t, rowsum, rowsumsq, gate_f,
                                        colsum_tok, colsumsq_tok, st4);

  pooled_k<<<32, 768, 0, stream>>>(colsum_tok, colsum_tsa, bstat_tsa, colsum_fsa,
                                   bstat_fsa, colsum_tgsa, bstat_tgsa, colsum_tsg,
                                   gate_f, st4, pooled);
  fnn1_k<<<dim3(6, 42), blk, 0, stream>>>(pooled, W1, tmp1);
  fnn2_k<<<24, blk, 0, stream>>>(tmp1, b1, W2, b2, out);
}

// Round 8
// 450.542 us; speedup vs baseline: 1.9107x; 1.9107x over previous
//
#include <hip/hip_runtime.h>
#include <cmath>

typedef unsigned short u16;
typedef __attribute__((ext_vector_type(4))) float f32x4;
typedef __attribute__((ext_vector_type(4))) unsigned int u32x4;
typedef __attribute__((ext_vector_type(8))) __bf16 bf16x8;

__device__ __forceinline__ u16 f2b(float f) {
  unsigned int u = __builtin_bit_cast(unsigned int, f);
  return (u16)((u + 0x7fffu + ((u >> 16) & 1u)) >> 16);  // RNE
}
__device__ __forceinline__ float b2f(u16 h) {
  unsigned int u = ((unsigned int)h) << 16;
  return __builtin_bit_cast(float, u);
}

__device__ __forceinline__ void glds16(const u16* g, u16* l) {
  __builtin_amdgcn_global_load_lds(
      (const __attribute__((address_space(1))) void*)g,
      (__attribute__((address_space(3))) void*)l, 16, 0, 0);
}

// ---------------------------------------------------------------------------
// Fast bf16-MFMA GEMM, 128x128 tile, BK=32, 256 threads (4 waves, 2x2).
// A: M x K row-major bf16 (lda), per-z stride sA; B: N x K row-major (ldb).
// global_load_lds w16, double-buffered, counted vmcnt, chunk swizzle on both
// global-src and ds_read sides. Bijective XCD block remap (nwg % 8 == 0).
// Epilogue stores go through L2 (NO nontemporal: L2 write-combining is what
// turns the partial-line bursts into full lines -- r7 lesson, 2x write blowup)
// EPI 0: fused QKV (N=2304, cbuf=tileN/768): C row-major + C^T packed 8B.
// EPI 1: TGSA reduce: v = sigmoid(acc+bias[n]) * tokb[m,n]; colsum/bsum/bsumsq
// EPI 2: store bf16 (acc*scale)  (attention scores; attN^T direct via operand
//        swap A=Kt,B=Qt)
// EPI 3: reduce-only: colsum[z,n], bsum[z], bsumsq[z]
// ---------------------------------------------------------------------------
template <int EPI>
__global__ __launch_bounds__(256) void gemm_f_k(
    const u16* __restrict__ Ap, const u16* __restrict__ Bp, u16* __restrict__ Cp,
    u16* __restrict__ CpT, const float* __restrict__ bias,
    const u16* __restrict__ tokp, float* __restrict__ colsum,
    float* __restrict__ bstat, int K, int lda, int ldb, int ldc, long sA,
    long sB, long sC, float scale) {
  __shared__ alignas(16) u16 smem[4][4096];  // A0,B0,A1,B1 : 128 rows x 32 u16
  __shared__ float scol_s[128];
  __shared__ float sred[2];

  // bijective XCD-chunked remap (nwg % 8 == 0 for all our grids)
  const int gx = gridDim.x, gxy = gx * gridDim.y;
  const int nwg = gxy * gridDim.z;
  int orig = (blockIdx.z * gridDim.y + blockIdx.y) * gx + blockIdx.x;
  int gwi = (orig & 7) * (nwg >> 3) + (orig >> 3);
  const int z = gwi / gxy;
  int rem = gwi - z * gxy;
  const int ty = rem / gx, tx = rem - ty * gx;
  const int tileM = ty << 7, tileN = tx << 7;

  const u16* Abase = Ap + (size_t)z * sA;
  const u16* Bbase = Bp + (size_t)z * sB;

  const int tid = threadIdx.x;
  const int lane = tid & 63, w = tid >> 6;
  const int wr = (w >> 1) << 6, wc = (w & 1) << 6;
  const int fr = lane & 15, fg = lane >> 4;

  f32x4 acc[4][4];
#pragma unroll
  for (int i = 0; i < 4; ++i)
#pragma unroll
    for (int j = 0; j < 4; ++j) acc[i][j] = (f32x4){0.f, 0.f, 0.f, 0.f};

  // staging: wave w covers rows [w*32, w*32+32); global col chunk pre-swizzled
  const int srow = (w << 5) + (lane >> 2);
  const int scol = (((lane & 3) ^ ((lane >> 3) & 3)) << 3);
  const u16* gA = Abase + (size_t)(tileM + srow) * lda + scol;
  const u16* gB = Bbase + (size_t)(tileN + srow) * ldb + scol;
  const int ldsw = (w << 5) * 32;  // u16 offset of wave's chunk

  auto STAGE = [&](int buf, int k0) {
    const u16* ga = gA + k0;
    const u16* gb = gB + k0;
    u16* la = &smem[buf * 2][ldsw];
    u16* lb = &smem[buf * 2 + 1][ldsw];
    glds16(ga, la);
    glds16(ga + (size_t)16 * lda, la + 512);
    glds16(gb, lb);
    glds16(gb + (size_t)16 * ldb, lb + 512);
  };

  // ds_read swizzle matches the pre-swizzled global source
  const int col_off = ((fg ^ ((fr >> 1) & 3)) << 3);

  const int nt = K >> 5;
  STAGE(0, 0);
  int cur = 0;
  for (int t = 0; t < nt; ++t) {
    if (t + 1 < nt) {
      STAGE(cur ^ 1, (t + 1) << 5);
      asm volatile("s_waitcnt vmcnt(4)" ::: "memory");
    } else {
      asm volatile("s_waitcnt vmcnt(0)" ::: "memory");
    }
    __builtin_amdgcn_s_barrier();
    asm volatile("" ::: "memory");
    const u16* Ab = smem[cur * 2];
    const u16* Bb = smem[cur * 2 + 1];
    bf16x8 av[4], bw[4];
#pragma unroll
    for (int m = 0; m < 4; ++m)
      av[m] = *(const bf16x8*)&Ab[(wr + (m << 4) + fr) * 32 + col_off];
#pragma unroll
    for (int n = 0; n < 4; ++n)
      bw[n] = *(const bf16x8*)&Bb[(wc + (n << 4) + fr) * 32 + col_off];
#pragma unroll
    for (int m = 0; m < 4; ++m)
#pragma unroll
      for (int n = 0; n < 4; ++n)
        acc[m][n] =
            __builtin_amdgcn_mfma_f32_16x16x32_bf16(av[m], bw[n], acc[m][n], 0, 0, 0);
    asm volatile("" ::: "memory");
    __builtin_amdgcn_s_barrier();
    cur ^= 1;
  }

  // ---- epilogue ----
  if constexpr (EPI == 0) {
    const int cbuf = tileN / 768;
    const int nbase = tileN - cbuf * 768;
    u16* Cz = Cp + (size_t)cbuf * sC;
#pragma unroll
    for (int m = 0; m < 4; ++m) {
#pragma unroll
      for (int n = 0; n < 4; ++n) {
        const int gcol = tileN + wc + (n << 4) + fr;
        const int lcol = nbase + wc + (n << 4) + fr;
        const float bv2 = bias[gcol];
#pragma unroll
        for (int r = 0; r < 4; ++r) {
          const int grow = tileM + wr + (m << 4) + (fg << 2) + r;
          Cz[(size_t)grow * 768 + lcol] = f2b(acc[m][n][r] + bv2);
        }
      }
    }
    u16* Ct = CpT + (size_t)cbuf * sC;
#pragma unroll
    for (int m = 0; m < 4; ++m) {
#pragma unroll
      for (int n = 0; n < 4; ++n) {
        const int gcol = tileN + wc + (n << 4) + fr;
        const int lcol = nbase + wc + (n << 4) + fr;
        const int grow0 = tileM + wr + (m << 4) + (fg << 2);
        union { u16 u[4]; unsigned long long q; } pk;
#pragma unroll
        for (int r = 0; r < 4; ++r) pk.u[r] = f2b(acc[m][n][r] + bias[gcol]);
        *(unsigned long long*)&Ct[(size_t)lcol * 16384 + grow0] = pk.q;
      }
    }
  } else if constexpr (EPI == 1) {
    // TGSA: v = sigmoid(acc + btg[n]) * tokb[m,n]
    if (tid < 128) scol_s[tid] = 0.f;
    if (tid == 0) { sred[0] = 0.f; sred[1] = 0.f; }
    __syncthreads();
    float ls = 0.f, lq = 0.f;
#pragma unroll
    for (int n = 0; n < 4; ++n) {
      float cpart = 0.f;
      const int gcol = tileN + wc + (n << 4) + fr;
      const float bv2 = bias[gcol];
#pragma unroll
      for (int m = 0; m < 4; ++m) {
#pragma unroll
        for (int r = 0; r < 4; ++r) {
          const int grow = tileM + wr + (m << 4) + (fg << 2) + r;
          float g = 1.f / (1.f + __expf(-(acc[m][n][r] + bv2)));
          float v = g * b2f(tokp[(size_t)grow * 768 + gcol]);
          cpart += v; ls += v; lq += v * v;
        }
      }
      atomicAdd(&scol_s[wc + (n << 4) + fr], cpart);
    }
    atomicAdd(&sred[0], ls);
    atomicAdd(&sred[1], lq);
    __syncthreads();
    const int b = tileM >> 9;
    if (tid < 128) atomicAdd(&colsum[(size_t)b * 768 + tileN + tid], scol_s[tid]);
    if (tid == 0) {
      atomicAdd(&bstat[b], sred[0]);
      atomicAdd(&bstat[32 + b], sred[1]);
    }
  } else if constexpr (EPI == 2) {
    u16* Cz = Cp + (size_t)z * sC;
#pragma unroll
    for (int m = 0; m < 4; ++m) {
#pragma unroll
      for (int n = 0; n < 4; ++n) {
        const int gcol = tileN + wc + (n << 4) + fr;
#pragma unroll
        for (int r = 0; r < 4; ++r) {
          const int grow = tileM + wr + (m << 4) + (fg << 2) + r;
          Cz[(size_t)grow * ldc + gcol] = f2b(acc[m][n][r] * scale);
        }
      }
    }
  } else {
    if (tid < 128) scol_s[tid] = 0.f;
    if (tid == 0) { sred[0] = 0.f; sred[1] = 0.f; }
    __syncthreads();
    float ls = 0.f, lq = 0.f;
#pragma unroll
    for (int n = 0; n < 4; ++n) {
      float cpart = 0.f;
#pragma unroll
      for (int m = 0; m < 4; ++m) {
#pragma unroll
        for (int r = 0; r < 4; ++r) {
          float v = acc[m][n][r];
          cpart += v; ls += v; lq += v * v;
        }
      }
      atomicAdd(&scol_s[wc + (n << 4) + fr], cpart);
    }
    atomicAdd(&sred[0], ls);
    atomicAdd(&sred[1], lq);
    __syncthreads();
    if (tid < 128) atomicAdd(&colsum[(size_t)z * 768 + tileN + tid], scol_s[tid]);
    if (tid == 0) {
      atomicAdd(&bstat[z], sred[0]);
      atomicAdd(&bstat[32 + z], sred[1]);
    }
  }
}

// fused: tokens f32 -> tokb bf16 + per-row gate_t/rowsum/rowsumsq. 1 wave/row.
__global__ __launch_bounds__(256) void cvt_row_k(
    const float* __restrict__ tok, u16* __restrict__ tokb,
    const float* __restrict__ Wts, const float* __restrict__ bts,
    float* __restrict__ gate_t, float* __restrict__ rowsum,
    float* __restrict__ rowsumsq) {
  const int w = threadIdx.x >> 6, lane = threadIdx.x & 63;
  const int row = blockIdx.x * 4 + w;
  const float* p = tok + (size_t)row * 768;
  u16* q = tokb + (size_t)row * 768;
  float s = 0.f, sq = 0.f, g = 0.f;
#pragma unroll
  for (int i = 0; i < 3; ++i) {
    const int idx = (i * 64 + lane) << 2;
    f32x4 v = *(const f32x4*)(p + idx);
    f32x4 wv = *(const f32x4*)(Wts + idx);
    union { u16 u[4]; unsigned long long q8; } pk;
#pragma unroll
    for (int j = 0; j < 4; ++j) {
      s += v[j]; sq += v[j] * v[j]; g += v[j] * wv[j];
      pk.u[j] = f2b(v[j]);
    }
    *(unsigned long long*)(q + idx) = pk.q8;
  }
#pragma unroll
  for (int o = 32; o > 0; o >>= 1) {
    s += __shfl_xor(s, o); sq += __shfl_xor(sq, o); g += __shfl_xor(g, o);
  }
  if (lane == 0) {
    gate_t[row] = fmaxf(g + bts[0], 0.f);
    rowsum[row] = s;
    rowsumsq[row] = sq;
  }
}

// W [768][768] f32 -> WT [768][768] bf16 (transposed)
__global__ __launch_bounds__(256) void transpose_w_k(const float* __restrict__ W,
                                                     u16* __restrict__ WT) {
  __shared__ float t[64][65];
  const int r0 = blockIdx.y << 6, c0 = blockIdx.x << 6;
  for (int i = threadIdx.x; i < 4096; i += 256) {
    int r = i >> 6, c = i & 63;
    t[r][c] = W[(size_t)(r0 + r) * 768 + c0 + c];
  }
  __syncthreads();
  for (int i = threadIdx.x; i < 4096; i += 256) {
    int rr = i >> 6, cc = i & 63;
    WT[(size_t)(c0 + rr) * 768 + r0 + cc] = f2b(t[cc][rr]);
  }
}

// in-place row softmax on bf16 scores; block=256, grid=numRows
template <int LEN>
__global__ __launch_bounds__(256) void softmax_k(u16* __restrict__ data) {
  constexpr int NP = LEN / 256;
  const int row = blockIdx.x, tid = threadIdx.x;
  u16* p = data + (size_t)row * LEN;
  const int lane = tid & 63, wid = tid >> 6;
  float v[NP];
  float mx = -1e30f;
#pragma unroll
  for (int i = 0; i < NP; ++i) { v[i] = b2f(p[tid + (i << 8)]); mx = fmaxf(mx, v[i]); }
#pragma unroll
  for (int o = 32; o > 0; o >>= 1) mx = fmaxf(mx, __shfl_xor(mx, o));
  __shared__ float red[4], red2[4];
  if (lane == 0) red[wid] = mx;
  __syncthreads();
  mx = fmaxf(fmaxf(red[0], red[1]), fmaxf(red[2], red[3]));
  float sum = 0.f;
#pragma unroll
  for (int i = 0; i < NP; ++i) { v[i] = __expf(v[i] - mx); sum += v[i]; }
#pragma unroll
  for (int o = 32; o > 0; o >>= 1) sum += __shfl_xor(sum, o);
  if (lane == 0) red2[wid] = sum;
  __syncthreads();
  sum = red2[0] + red2[1] + red2[2] + red2[3];
  const float inv = 1.f / sum;
#pragma unroll
  for (int i = 0; i < NP; ++i) p[tid + (i << 8)] = f2b(v[i] * inv);
}

// tiled column softmax on attNt [32][768 g][768 h]: softmax over g per (b,h).
// Block = (b, 64-h slice), 256 thr. Chunks of 32 g staged in LDS via 16B
// coalesced row loads; per-column online max/sum in registers.
__global__ __launch_bounds__(256) void colsoftmax_k(u16* __restrict__ data) {
  __shared__ u16 tile[32][72];
  __shared__ float sm[4][64], ss[4][64];
  const int tid = threadIdx.x;
  const int b = blockIdx.x;
  u16* base = data + (size_t)b * 589824 + (blockIdx.y << 6);
  const int lr = tid >> 3, seg = (tid & 7) << 3;   // load map: row, 16B seg
  const int c = tid & 63, q = tid >> 6;            // reduce map: col, quarter
  float m = -1e30f, s = 0.f;
  for (int ch = 0; ch < 24; ++ch) {
    u16* g = base + (size_t)(ch * 32 + lr) * 768 + seg;
    *(u32x4*)&tile[lr][seg] = *(const u32x4*)g;
    __syncthreads();
#pragma unroll
    for (int i = 0; i < 8; ++i) {
      float v = b2f(tile[(q << 3) + i][c]);
      float mn = fmaxf(m, v);
      s = s * __expf(m - mn) + __expf(v - mn);
      m = mn;
    }
    __syncthreads();
  }
  sm[q][c] = m; ss[q][c] = s;
  __syncthreads();
  const float M = fmaxf(fmaxf(sm[0][c], sm[1][c]), fmaxf(sm[2][c], sm[3][c]));
  const float S = ss[0][c] * __expf(sm[0][c] - M) + ss[1][c] * __expf(sm[1][c] - M) +
                  ss[2][c] * __expf(sm[2][c] - M) + ss[3][c] * __expf(sm[3][c] - M);
  const float inv = 1.f / S;
  for (int ch = 0; ch < 24; ++ch) {
    u16* g = base + (size_t)(ch * 32 + lr) * 768 + seg;
    *(u32x4*)&tile[lr][seg] = *(const u32x4*)g;
    __syncthreads();
#pragma unroll
    for (int i = 0; i < 8; ++i) {
      const int r = (q << 3) + i;
      tile[r][c] = f2b(__expf(b2f(tile[r][c]) - M) * inv);
    }
    __syncthreads();
    *(u32x4*)g = *(const u32x4*)&tile[lr][seg];
    __syncthreads();
  }
}

// per-column stats from tokb: gate_f, colsum_tok, colsumsq_tok, colsum_tsgsa.
__global__ __launch_bounds__(256) void col_stats_k(
    const u16* __restrict__ tokb, const float* __restrict__ Wfs,
    const float* __restrict__ bfs, const float* __restrict__ gate_t,
    float* __restrict__ gate_f, float* __restrict__ colsum_tok,
    float* __restrict__ colsumsq_tok, float* __restrict__ colsum_tsg) {
  const int b = blockIdx.x, h = blockIdx.y * 256 + threadIdx.x;
  const u16* p = tokb + (size_t)b * 512 * 768 + h;
  const float* gt = gate_t + b * 512;
  float cs = 0.f, cq = 0.f, gf = 0.f, tg = 0.f;
#pragma unroll 4
  for (int s = 0; s < 512; ++s) {
    float t = b2f(p[(size_t)s * 768]);
    cs += t; cq += t * t; gf += t * Wfs[s]; tg += t * gt[s];
  }
  const int idx = b * 768 + h;
  gate_f[idx] = fmaxf(gf + bfs[0], 0.f);
  colsum_tok[idx] = cs;
  colsumsq_tok[idx] = cq;
  colsum_tsg[idx] = tg;
}

// per-batch scalar stats for TSGSA and FSGSA. st: [tsg_s|tsg_q|fsg_s|fsg_q]x32
__global__ __launch_bounds__(256) void batch_stats_k(
    const float* __restrict__ gate_t, const float* __restrict__ rowsum,
    const float* __restrict__ rowsumsq, const float* __restrict__ gate_f,
    const float* __restrict__ colsum_tok, const float* __restrict__ colsumsq_tok,
    float* __restrict__ st) {
  __shared__ float red[4][256];
  const int b = blockIdx.x, tid = threadIdx.x;
  float ts = 0.f, tq = 0.f, fs = 0.f, fq = 0.f;
  for (int s = tid; s < 512; s += 256) {
    float g = gate_t[b * 512 + s];
    ts += g * rowsum[b * 512 + s];
    tq += g * g * rowsumsq[b * 512 + s];
  }
  for (int h = tid; h < 768; h += 256) {
    float g = gate_f[b * 768 + h];
    fs += g * colsum_tok[b * 768 + h];
    fq += g * g * colsumsq_tok[b * 768 + h];
  }
  red[0][tid] = ts; red[1][tid] = tq; red[2][tid] = fs; red[3][tid] = fq;
  __syncthreads();
  for (int o = 128; o > 0; o >>= 1) {
    if (tid < o) {
      red[0][tid] += red[0][tid + o];
      red[1][tid] += red[1][tid + o];
      red[2][tid] += red[2][tid + o];
      red[3][tid] += red[3][tid + o];
    }
    __syncthreads();
  }
  if (tid == 0) {
    st[b] = red[0][0]; st[32 + b] = red[1][0];
    st[64 + b] = red[2][0]; st[96 + b] = red[3][0];
  }
}

// build pooled [B, 7*768] from column sums + batch stats
__global__ __launch_bounds__(768) void pooled_k(
    const float* __restrict__ colsum_tok, const float* __restrict__ colsum_tsa,
    const float* __restrict__ bstat_tsa, const float* __restrict__ colsum_fsa,
    const float* __restrict__ bstat_fsa, const float* __restrict__ colsum_tgsa,
    const float* __restrict__ bstat_tgsa, const float* __restrict__ colsum_tsg,
    const float* __restrict__ gate_f, const float* __restrict__ st,
    float* __restrict__ pooled) {
  const int b = blockIdx.x, h = threadIdx.x;
  const float invS = 1.f / 512.f, invN = 1.f / (512.f * 768.f);
  const int i = b * 768 + h;
  float* pr = pooled + (size_t)b * 5376;
  pr[h] = colsum_tok[i] * invS;
  auto lnslot = [&](int slot, float cs, float bs, float bq) {
    float m = bs * invN;
    float var = bq * invN - m * m;
    pr[slot * 768 + h] = (cs * invS - m) * rsqrtf(var + 1e-8f);
  };
  lnslot(1, colsum_tsa[i], bstat_tsa[b], bstat_tsa[32 + b]);
  lnslot(2, colsum_fsa[i], bstat_fsa[b], bstat_fsa[32 + b]);
  lnslot(3, colsum_tgsa[i], bstat_tgsa[b], bstat_tgsa[32 + b]);
  const float fsg_cs = gate_f[i] * colsum_tok[i];
  lnslot(4, fsg_cs, st[64 + b], st[96 + b]);
  lnslot(5, colsum_tsg[i], st[b], st[32 + b]);
  lnslot(6, fsg_cs, st[64 + b], st[96 + b]);
}

// tmp1 += pooled-slice . W1-slice.  grid (6 colchunks, 42 kchunks), 256 thr.
__global__ __launch_bounds__(256) void fnn1_k(const float* __restrict__ pooled,
                                              const float* __restrict__ W1,
                                              float* __restrict__ tmp1) {
  __shared__ float sp[128][36];
  const int c0 = blockIdx.x << 7, k0 = blockIdx.y << 7;
  const int tid = threadIdx.x;
  for (int i = tid; i < 4096; i += 256) {
    int b = i >> 7, j = i & 127;
    sp[j][b] = pooled[(size_t)b * 5376 + k0 + j];
  }
  __syncthreads();
  const int c = c0 + (tid & 127);
  const int u = (tid >> 7) << 4;
  float acc[16];
#pragma unroll
  for (int t = 0; t < 16; ++t) acc[t] = 0.f;
#pragma unroll 4
  for (int j = 0; j < 128; ++j) {
    float w = W1[(size_t)(k0 + j) * 768 + c];
    const f32x4* row = (const f32x4*)&sp[j][u];
#pragma unroll
    for (int t4 = 0; t4 < 4; ++t4) {
      f32x4 v = row[t4];
#pragma unroll
      for (int r = 0; r < 4; ++r) acc[t4 * 4 + r] += v[r] * w;
    }
  }
#pragma unroll
  for (int t = 0; t < 16; ++t) atomicAdd(&tmp1[(u + t) * 768 + c], acc[t]);
}

// out[b,c] = sum_k (tmp1[b,k]+b1[k]) * W2[k,c] + b2[c].  One wave per output.
__global__ __launch_bounds__(256) void fnn2_k(const float* __restrict__ tmp1,
                                              const float* __restrict__ b1,
                                              const float* __restrict__ W2,
                                              const float* __restrict__ b2,
                                              float* __restrict__ out) {
  const int gw = blockIdx.x * 4 + (threadIdx.x >> 6);
  const int lane = threadIdx.x & 63;
  const int b = gw / 3, c = gw % 3;
  float a = 0.f;
#pragma unroll
  for (int i = 0; i < 12; ++i) {
    int k = lane + i * 64;
    a += (tmp1[b * 768 + k] + b1[k]) * W2[k * 3 + c];
  }
#pragma unroll
  for (int o = 32; o > 0; o >>= 1) a += __shfl_xor(a, o);
  if (lane == 0) out[b * 3 + c] = a + b2[c];
}

extern "C" void kernel_launch(void* const* d_in, const int* in_sizes, int n_in,
                              void* d_out, int out_size, void* d_ws, size_t ws_size,
                              hipStream_t stream) {
  const float* tokens = (const float*)d_in[0];
  const float* Wq = (const float*)d_in[1];
  const float* bq = (const float*)d_in[2];
  const float* Wk = (const float*)d_in[3];
  const float* bk = (const float*)d_in[4];
  const float* Wv = (const float*)d_in[5];
  const float* bv = (const float*)d_in[6];
  const float* Wts = (const float*)d_in[7];
  const float* bts = (const float*)d_in[8];
  const float* Wfs = (const float*)d_in[9];
  const float* bfs = (const float*)d_in[10];
  const float* Wtg = (const float*)d_in[11];
  const float* btg = (const float*)d_in[12];
  const float* W1 = (const float*)d_in[13];
  const float* b1 = (const float*)d_in[14];
  const float* W2 = (const float*)d_in[15];
  const float* b2 = (const float*)d_in[16];
  float* out = (float*)d_out;

  char* ws = (char*)d_ws;
  size_t off = 0;
  auto take = [&](size_t bytes) -> char* {
    char* p = ws + off;
    off += (bytes + 255) & ~(size_t)255;
    return p;
  };
  u16* tokb = (u16*)take((size_t)16384 * 768 * 2);
  u16* WqT = (u16*)take((size_t)768 * 768 * 2);  // WqT/WkT/WvT contiguous
  u16* WkT = (u16*)take((size_t)768 * 768 * 2);
  u16* WvT = (u16*)take((size_t)768 * 768 * 2);
  u16* WtgT = (u16*)take((size_t)768 * 768 * 2);
  u16* Qb = (u16*)take((size_t)16384 * 768 * 2);  // Qb/Kb/Vb contiguous
  u16* Kb = (u16*)take((size_t)16384 * 768 * 2);
  u16* Vb = (u16*)take((size_t)16384 * 768 * 2);
  u16* Qt = (u16*)take((size_t)768 * 16384 * 2);  // Qt/Kt/Vt contiguous
  u16* Kt = (u16*)take((size_t)768 * 16384 * 2);
  u16* Vt = (u16*)take((size_t)768 * 16384 * 2);
  u16* attb = (u16*)take((size_t)32 * 512 * 512 * 2);
  u16* attNt = (u16*)take((size_t)32 * 768 * 768 * 2);  // attN^T [b][g][h]
  float* bias3 = (float*)take(2304 * 4);
  // --- zeroed (atomic-accumulated) region: keep contiguous ---
  char* zbase = ws + off;
  float* colsum_tsa = (float*)take(24576 * 4);
  float* colsum_fsa = (float*)take(24576 * 4);
  float* colsum_tgsa = (float*)take(24576 * 4);
  float* bstat_tsa = (float*)take(64 * 4);
  float* bstat_fsa = (float*)take(64 * 4);
  float* bstat_tgsa = (float*)take(64 * 4);
  float* tmp1 = (float*)take((size_t)32 * 768 * 4);
  size_t zbytes = (size_t)((ws + off) - zbase);
  // --- fully-overwritten buffers ---
  float* colsum_tsg = (float*)take(24576 * 4);
  float* gate_t = (float*)take(16384 * 4);
  float* rowsum = (float*)take(16384 * 4);
  float* rowsumsq = (float*)take(16384 * 4);
  float* gate_f = (float*)take(24576 * 4);
  float* colsum_tok = (float*)take(24576 * 4);
  float* colsumsq_tok = (float*)take(24576 * 4);
  float* st4 = (float*)take(128 * 4);
  float* pooled = (float*)take((size_t)32 * 5376 * 4);

  hipMemsetAsync(zbase, 0, zbytes, stream);
  hipMemcpyAsync(bias3, bq, 768 * 4, hipMemcpyDeviceToDevice, stream);
  hipMemcpyAsync(bias3 + 768, bk, 768 * 4, hipMemcpyDeviceToDevice, stream);
  hipMemcpyAsync(bias3 + 1536, bv, 768 * 4, hipMemcpyDeviceToDevice, stream);

  const float scale = 1.0f / sqrtf(768.0f);
  const dim3 blk(256);

  // prep: tokens->bf16 + row stats (fused); weights->transposed bf16
  cvt_row_k<<<4096, blk, 0, stream>>>(tokens, tokb, Wts, bts, gate_t, rowsum,
                                      rowsumsq);
  transpose_w_k<<<dim3(12, 12), blk, 0, stream>>>(Wq, WqT);
  transpose_w_k<<<dim3(12, 12), blk, 0, stream>>>(Wk, WkT);
  transpose_w_k<<<dim3(12, 12), blk, 0, stream>>>(Wv, WvT);
  transpose_w_k<<<dim3(12, 12), blk, 0, stream>>>(Wtg, WtgT);

  // fused Q|K|V projection: N=2304 (B panel 3.5MB fits per-XCD L2)
  gemm_f_k<0><<<dim3(18, 128, 1), blk, 0, stream>>>(
      tokb, WqT, Qb, Qt, bias3, nullptr, nullptr, nullptr, 768, 768, 768, 768,
      0, 0, 12582912, 0.f);
  // TGSA (gated reduce), reads tokb
  gemm_f_k<1><<<dim3(6, 128, 1), blk, 0, stream>>>(
      tokb, WtgT, nullptr, nullptr, btg, tokb, colsum_tgsa, bstat_tgsa, 768,
      768, 768, 0, 0, 0, 0, 0.f);

  // attN^T directly: attNt[g][h] = sum_s Kt[g][s] Qt[h][s]  (operand swap)
  gemm_f_k<2><<<dim3(6, 6, 32), blk, 0, stream>>>(
      Kt, Qt, attNt, nullptr, nullptr, nullptr, nullptr, nullptr, 512, 16384,
      16384, 768, 512, 512, 589824, scale);
  colsoftmax_k<<<dim3(32, 12), blk, 0, stream>>>(attNt);

  // token attention scores: att[s,t] = Q[s,:].K[t,:] * scale
  gemm_f_k<2><<<dim3(4, 4, 32), blk, 0, stream>>>(
      Qb, Kb, attb, nullptr, nullptr, nullptr, nullptr, nullptr, 768, 768, 768,
      512, 393216, 393216, 262144, scale);
  softmax_k<512><<<16384, 256, 0, stream>>>(attb);

  // TSA = att @ V  -> reduce only
  gemm_f_k<3><<<dim3(6, 4, 32), blk, 0, stream>>>(
      attb, Vt, nullptr, nullptr, nullptr, nullptr, colsum_tsa, bstat_tsa, 512,
      512, 16384, 0, 262144, 512, 0, 0.f);
  // FSA = V @ attN -> reduce only  (B rows = attNt rows g)
  gemm_f_k<3><<<dim3(6, 4, 32), blk, 0, stream>>>(
      Vb, attNt, nullptr, nullptr, nullptr, nullptr, colsum_fsa, bstat_fsa, 768,
      768, 768, 0, 393216, 589824, 0, 0.f);

  // remaining gate-branch statistics
  col_stats_k<<<dim3(32, 3), blk, 0, stream>>>(tokb, Wfs, bfs, gate_t, gate_f,
                                               colsum_tok, colsumsq_tok, colsum_tsg);
  batch_stats_k<<<32, blk, 0, stream>>>(gate_t, rowsum, rowsumsq, gate_f,
                                        colsum_tok, colsumsq_tok, st4);

  pooled_k<<<32, 768, 0, stream>>>(colsum_tok, colsum_tsa, bstat_tsa, colsum_fsa,
                                   bstat_fsa, colsum_tgsa, bstat_tgsa, colsum_tsg,
                                   gate_f, st4, pooled);
  fnn1_k<<<dim3(6, 42), blk, 0, stream>>>(pooled, W1, tmp1);
  fnn2_k<<<24, blk, 0, stream>>>(tmp1, b1, W2, b2, out);
}

// Round 9
// 438.234 us; speedup vs baseline: 1.9644x; 1.0281x over previous
//
#include <hip/hip_runtime.h>
#include <cmath>

typedef unsigned short u16;
typedef __attribute__((ext_vector_type(4))) float f32x4;
typedef __attribute__((ext_vector_type(4))) unsigned int u32x4;
typedef __attribute__((ext_vector_type(8))) __bf16 bf16x8;

__device__ __forceinline__ u16 f2b(float f) {
  unsigned int u = __builtin_bit_cast(unsigned int, f);
  return (u16)((u + 0x7fffu + ((u >> 16) & 1u)) >> 16);  // RNE
}
__device__ __forceinline__ float b2f(u16 h) {
  unsigned int u = ((unsigned int)h) << 16;
  return __builtin_bit_cast(float, u);
}

__device__ __forceinline__ void glds16(const u16* g, u16* l) {
  __builtin_amdgcn_global_load_lds(
      (const __attribute__((address_space(1))) void*)g,
      (__attribute__((address_space(3))) void*)l, 16, 0, 0);
}

// ---------------------------------------------------------------------------
// Fast bf16-MFMA GEMM, 256x128 tile, BK=32, 512 threads (8 waves, 4x2).
// Per-wave structure identical to the verified 128x128/4-wave engine (64x64
// wave tile, acc[4][4], same chunk swizzle on global-src and ds_read sides);
// BM=256 halves barrier+stage cost per FLOP and halves A-panel HBM refetch.
// A: M x K row-major bf16 (lda), per-z stride sA; B: N x K row-major (ldb).
// global_load_lds w16, double-buffered, counted vmcnt(3). Bijective XCD
// block remap (nwg % 8 == 0). Stores through L2 (no nontemporal - r7 lesson).
// EPI 0: fused QKV (N=2304, cbuf=tileN/768): C row-major + C^T packed 8B.
// EPI 1: TGSA reduce: v = sigmoid(acc+bias[n]) * tokb[m,n]; colsum/bsum/bsumsq
// EPI 2: store bf16 (acc*scale)  (attention scores; attN^T direct via operand
//        swap A=Kt,B=Qt)
// EPI 3: reduce-only: colsum[z,n], bsum[z], bsumsq[z]
// ---------------------------------------------------------------------------
template <int EPI>
__global__ __launch_bounds__(512) void gemm_f_k(
    const u16* __restrict__ Ap, const u16* __restrict__ Bp, u16* __restrict__ Cp,
    u16* __restrict__ CpT, const float* __restrict__ bias,
    const u16* __restrict__ tokp, float* __restrict__ colsum,
    float* __restrict__ bstat, int K, int lda, int ldb, int ldc, long sA,
    long sB, long sC, float scale) {
  __shared__ alignas(16) u16 Asm[2][8192];  // 256 rows x 32 u16, dbuf
  __shared__ alignas(16) u16 Bsm[2][4096];  // 128 rows x 32 u16, dbuf
  __shared__ float scol_s[128];
  __shared__ float sred[2];

  // bijective XCD-chunked remap (nwg % 8 == 0 for all our grids)
  const int gx = gridDim.x, gxy = gx * gridDim.y;
  const int nwg = gxy * gridDim.z;
  int orig = (blockIdx.z * gridDim.y + blockIdx.y) * gx + blockIdx.x;
  int gwi = (orig & 7) * (nwg >> 3) + (orig >> 3);
  const int z = gwi / gxy;
  int rem = gwi - z * gxy;
  const int ty = rem / gx, tx = rem - ty * gx;
  const int tileM = ty << 8, tileN = tx << 7;

  const u16* Abase = Ap + (size_t)z * sA;
  const u16* Bbase = Bp + (size_t)z * sB;

  const int tid = threadIdx.x;
  const int lane = tid & 63, w = tid >> 6;          // w in [0,8)
  const int wr = (w >> 1) << 6, wc = (w & 1) << 6;  // 4 row-waves x 2 col-waves
  const int fr = lane & 15, fg = lane >> 4;

  f32x4 acc[4][4];
#pragma unroll
  for (int i = 0; i < 4; ++i)
#pragma unroll
    for (int j = 0; j < 4; ++j) acc[i][j] = (f32x4){0.f, 0.f, 0.f, 0.f};

  // staging: wave w covers A rows [w*32,w*32+32) and B rows [w*16,w*16+16).
  // global col chunk pre-swizzled; LDS row r chunk c holds global chunk
  // c ^ ((r>>1)&3)  (invariant for both 32-row and 16-row wave strides).
  const int sArow = (w << 5) + (lane >> 2);
  const int sBrow = (w << 4) + (lane >> 2);
  const int scol = (((lane & 3) ^ ((lane >> 3) & 3)) << 3);
  const u16* gA = Abase + (size_t)(tileM + sArow) * lda + scol;
  const u16* gB = Bbase + (size_t)(tileN + sBrow) * ldb + scol;
  const int ldsA = (w << 5) * 32;  // u16 offset of wave's A chunk
  const int ldsB = (w << 4) * 32;  // u16 offset of wave's B chunk

  auto STAGE = [&](int buf, int k0) {
    glds16(gA + k0, &Asm[buf][ldsA]);
    glds16(gA + (size_t)16 * lda + k0, &Asm[buf][ldsA + 512]);
    glds16(gB + k0, &Bsm[buf][ldsB]);
  };

  // ds_read swizzle matches the pre-swizzled global source
  const int col_off = ((fg ^ ((fr >> 1) & 3)) << 3);

  const int nt = K >> 5;
  STAGE(0, 0);
  int cur = 0;
  for (int t = 0; t < nt; ++t) {
    if (t + 1 < nt) {
      STAGE(cur ^ 1, (t + 1) << 5);
      asm volatile("s_waitcnt vmcnt(3)" ::: "memory");
    } else {
      asm volatile("s_waitcnt vmcnt(0)" ::: "memory");
    }
    __builtin_amdgcn_s_barrier();
    asm volatile("" ::: "memory");
    const u16* Ab = Asm[cur];
    const u16* Bb = Bsm[cur];
    bf16x8 av[4], bw[4];
#pragma unroll
    for (int m = 0; m < 4; ++m)
      av[m] = *(const bf16x8*)&Ab[(wr + (m << 4) + fr) * 32 + col_off];
#pragma unroll
    for (int n = 0; n < 4; ++n)
      bw[n] = *(const bf16x8*)&Bb[(wc + (n << 4) + fr) * 32 + col_off];
#pragma unroll
    for (int m = 0; m < 4; ++m)
#pragma unroll
      for (int n = 0; n < 4; ++n)
        acc[m][n] =
            __builtin_amdgcn_mfma_f32_16x16x32_bf16(av[m], bw[n], acc[m][n], 0, 0, 0);
    asm volatile("" ::: "memory");
    __builtin_amdgcn_s_barrier();
    cur ^= 1;
  }

  // ---- epilogue ----  (wave tile rows: tileM + wr*? -> wr in {0,64,128,192})
  if constexpr (EPI == 0) {
    const int cbuf = tileN / 768;
    const int nbase = tileN - cbuf * 768;
    u16* Cz = Cp + (size_t)cbuf * sC;
#pragma unroll
    for (int m = 0; m < 4; ++m) {
#pragma unroll
      for (int n = 0; n < 4; ++n) {
        const int gcol = tileN + wc + (n << 4) + fr;
        const int lcol = nbase + wc + (n << 4) + fr;
        const float bv2 = bias[gcol];
#pragma unroll
        for (int r = 0; r < 4; ++r) {
          const int grow = tileM + wr + (m << 4) + (fg << 2) + r;
          Cz[(size_t)grow * 768 + lcol] = f2b(acc[m][n][r] + bv2);
        }
      }
    }
    u16* Ct = CpT + (size_t)cbuf * sC;
#pragma unroll
    for (int m = 0; m < 4; ++m) {
#pragma unroll
      for (int n = 0; n < 4; ++n) {
        const int gcol = tileN + wc + (n << 4) + fr;
        const int lcol = nbase + wc + (n << 4) + fr;
        const int grow0 = tileM + wr + (m << 4) + (fg << 2);
        union { u16 u[4]; unsigned long long q; } pk;
#pragma unroll
        for (int r = 0; r < 4; ++r) pk.u[r] = f2b(acc[m][n][r] + bias[gcol]);
        *(unsigned long long*)&Ct[(size_t)lcol * 16384 + grow0] = pk.q;
      }
    }
  } else if constexpr (EPI == 1) {
    // TGSA: v = sigmoid(acc + btg[n]) * tokb[m,n]
    if (tid < 128) scol_s[tid] = 0.f;
    if (tid == 0) { sred[0] = 0.f; sred[1] = 0.f; }
    __syncthreads();
    float ls = 0.f, lq = 0.f;
#pragma unroll
    for (int n = 0; n < 4; ++n) {
      float cpart = 0.f;
      const int gcol = tileN + wc + (n << 4) + fr;
      const float bv2 = bias[gcol];
#pragma unroll
      for (int m = 0; m < 4; ++m) {
#pragma unroll
        for (int r = 0; r < 4; ++r) {
          const int grow = tileM + wr + (m << 4) + (fg << 2) + r;
          float g = 1.f / (1.f + __expf(-(acc[m][n][r] + bv2)));
          float v = g * b2f(tokp[(size_t)grow * 768 + gcol]);
          cpart += v; ls += v; lq += v * v;
        }
      }
      atomicAdd(&scol_s[wc + (n << 4) + fr], cpart);
    }
    atomicAdd(&sred[0], ls);
    atomicAdd(&sred[1], lq);
    __syncthreads();
    const int b = tileM >> 9;
    if (tid < 128) atomicAdd(&colsum[(size_t)b * 768 + tileN + tid], scol_s[tid]);
    if (tid == 0) {
      atomicAdd(&bstat[b], sred[0]);
      atomicAdd(&bstat[32 + b], sred[1]);
    }
  } else if constexpr (EPI == 2) {
    u16* Cz = Cp + (size_t)z * sC;
#pragma unroll
    for (int m = 0; m < 4; ++m) {
#pragma unroll
      for (int n = 0; n < 4; ++n) {
        const int gcol = tileN + wc + (n << 4) + fr;
#pragma unroll
        for (int r = 0; r < 4; ++r) {
          const int grow = tileM + wr + (m << 4) + (fg << 2) + r;
          Cz[(size_t)grow * ldc + gcol] = f2b(acc[m][n][r] * scale);
        }
      }
    }
  } else {
    if (tid < 128) scol_s[tid] = 0.f;
    if (tid == 0) { sred[0] = 0.f; sred[1] = 0.f; }
    __syncthreads();
    float ls = 0.f, lq = 0.f;
#pragma unroll
    for (int n = 0; n < 4; ++n) {
      float cpart = 0.f;
#pragma unroll
      for (int m = 0; m < 4; ++m) {
#pragma unroll
        for (int r = 0; r < 4; ++r) {
          float v = acc[m][n][r];
          cpart += v; ls += v; lq += v * v;
        }
      }
      atomicAdd(&scol_s[wc + (n << 4) + fr], cpart);
    }
    atomicAdd(&sred[0], ls);
    atomicAdd(&sred[1], lq);
    __syncthreads();
    if (tid < 128) atomicAdd(&colsum[(size_t)z * 768 + tileN + tid], scol_s[tid]);
    if (tid == 0) {
      atomicAdd(&bstat[z], sred[0]);
      atomicAdd(&bstat[32 + z], sred[1]);
    }
  }
}

// fused: tokens f32 -> tokb bf16 + per-row gate_t/rowsum/rowsumsq. 1 wave/row.
__global__ __launch_bounds__(256) void cvt_row_k(
    const float* __restrict__ tok, u16* __restrict__ tokb,
    const float* __restrict__ Wts, const float* __restrict__ bts,
    float* __restrict__ gate_t, float* __restrict__ rowsum,
    float* __restrict__ rowsumsq) {
  const int w = threadIdx.x >> 6, lane = threadIdx.x & 63;
  const int row = blockIdx.x * 4 + w;
  const float* p = tok + (size_t)row * 768;
  u16* q = tokb + (size_t)row * 768;
  float s = 0.f, sq = 0.f, g = 0.f;
#pragma unroll
  for (int i = 0; i < 3; ++i) {
    const int idx = (i * 64 + lane) << 2;
    f32x4 v = *(const f32x4*)(p + idx);
    f32x4 wv = *(const f32x4*)(Wts + idx);
    union { u16 u[4]; unsigned long long q8; } pk;
#pragma unroll
    for (int j = 0; j < 4; ++j) {
      s += v[j]; sq += v[j] * v[j]; g += v[j] * wv[j];
      pk.u[j] = f2b(v[j]);
    }
    *(unsigned long long*)(q + idx) = pk.q8;
  }
#pragma unroll
  for (int o = 32; o > 0; o >>= 1) {
    s += __shfl_xor(s, o); sq += __shfl_xor(sq, o); g += __shfl_xor(g, o);
  }
  if (lane == 0) {
    gate_t[row] = fmaxf(g + bts[0], 0.f);
    rowsum[row] = s;
    rowsumsq[row] = sq;
  }
}

// W [768][768] f32 -> WT [768][768] bf16 (transposed)
__global__ __launch_bounds__(256) void transpose_w_k(const float* __restrict__ W,
                                                     u16* __restrict__ WT) {
  __shared__ float t[64][65];
  const int r0 = blockIdx.y << 6, c0 = blockIdx.x << 6;
  for (int i = threadIdx.x; i < 4096; i += 256) {
    int r = i >> 6, c = i & 63;
    t[r][c] = W[(size_t)(r0 + r) * 768 + c0 + c];
  }
  __syncthreads();
  for (int i = threadIdx.x; i < 4096; i += 256) {
    int rr = i >> 6, cc = i & 63;
    WT[(size_t)(c0 + rr) * 768 + r0 + cc] = f2b(t[cc][rr]);
  }
}

// in-place row softmax on bf16 scores; block=256, grid=numRows
template <int LEN>
__global__ __launch_bounds__(256) void softmax_k(u16* __restrict__ data) {
  constexpr int NP = LEN / 256;
  const int row = blockIdx.x, tid = threadIdx.x;
  u16* p = data + (size_t)row * LEN;
  const int lane = tid & 63, wid = tid >> 6;
  float v[NP];
  float mx = -1e30f;
#pragma unroll
  for (int i = 0; i < NP; ++i) { v[i] = b2f(p[tid + (i << 8)]); mx = fmaxf(mx, v[i]); }
#pragma unroll
  for (int o = 32; o > 0; o >>= 1) mx = fmaxf(mx, __shfl_xor(mx, o));
  __shared__ float red[4], red2[4];
  if (lane == 0) red[wid] = mx;
  __syncthreads();
  mx = fmaxf(fmaxf(red[0], red[1]), fmaxf(red[2], red[3]));
  float sum = 0.f;
#pragma unroll
  for (int i = 0; i < NP; ++i) { v[i] = __expf(v[i] - mx); sum += v[i]; }
#pragma unroll
  for (int o = 32; o > 0; o >>= 1) sum += __shfl_xor(sum, o);
  if (lane == 0) red2[wid] = sum;
  __syncthreads();
  sum = red2[0] + red2[1] + red2[2] + red2[3];
  const float inv = 1.f / sum;
#pragma unroll
  for (int i = 0; i < NP; ++i) p[tid + (i << 8)] = f2b(v[i] * inv);
}

// tiled column softmax on attNt [32][768 g][768 h]: softmax over g per (b,h).
// Block = (b, 64-h slice), 256 thr. Chunks of 32 g staged in LDS via 16B
// coalesced row loads; per-column online max/sum in registers.
__global__ __launch_bounds__(256) void colsoftmax_k(u16* __restrict__ data) {
  __shared__ u16 tile[32][72];
  __shared__ float sm[4][64], ss[4][64];
  const int tid = threadIdx.x;
  const int b = blockIdx.x;
  u16* base = data + (size_t)b * 589824 + (blockIdx.y << 6);
  const int lr = tid >> 3, seg = (tid & 7) << 3;   // load map: row, 16B seg
  const int c = tid & 63, q = tid >> 6;            // reduce map: col, quarter
  float m = -1e30f, s = 0.f;
  for (int ch = 0; ch < 24; ++ch) {
    u16* g = base + (size_t)(ch * 32 + lr) * 768 + seg;
    *(u32x4*)&tile[lr][seg] = *(const u32x4*)g;
    __syncthreads();
#pragma unroll
    for (int i = 0; i < 8; ++i) {
      float v = b2f(tile[(q << 3) + i][c]);
      float mn = fmaxf(m, v);
      s = s * __expf(m - mn) + __expf(v - mn);
      m = mn;
    }
    __syncthreads();
  }
  sm[q][c] = m; ss[q][c] = s;
  __syncthreads();
  const float M = fmaxf(fmaxf(sm[0][c], sm[1][c]), fmaxf(sm[2][c], sm[3][c]));
  const float S = ss[0][c] * __expf(sm[0][c] - M) + ss[1][c] * __expf(sm[1][c] - M) +
                  ss[2][c] * __expf(sm[2][c] - M) + ss[3][c] * __expf(sm[3][c] - M);
  const float inv = 1.f / S;
  for (int ch = 0; ch < 24; ++ch) {
    u16* g = base + (size_t)(ch * 32 + lr) * 768 + seg;
    *(u32x4*)&tile[lr][seg] = *(const u32x4*)g;
    __syncthreads();
#pragma unroll
    for (int i = 0; i < 8; ++i) {
      const int r = (q << 3) + i;
      tile[r][c] = f2b(__expf(b2f(tile[r][c]) - M) * inv);
    }
    __syncthreads();
    *(u32x4*)g = *(const u32x4*)&tile[lr][seg];
    __syncthreads();
  }
}

// per-column stats from tokb: gate_f, colsum_tok, colsumsq_tok, colsum_tsgsa.
__global__ __launch_bounds__(256) void col_stats_k(
    const u16* __restrict__ tokb, const float* __restrict__ Wfs,
    const float* __restrict__ bfs, const float* __restrict__ gate_t,
    float* __restrict__ gate_f, float* __restrict__ colsum_tok,
    float* __restrict__ colsumsq_tok, float* __restrict__ colsum_tsg) {
  const int b = blockIdx.x, h = blockIdx.y * 256 + threadIdx.x;
  const u16* p = tokb + (size_t)b * 512 * 768 + h;
  const float* gt = gate_t + b * 512;
  float cs = 0.f, cq = 0.f, gf = 0.f, tg = 0.f;
#pragma unroll 4
  for (int s = 0; s < 512; ++s) {
    float t = b2f(p[(size_t)s * 768]);
    cs += t; cq += t * t; gf += t * Wfs[s]; tg += t * gt[s];
  }
  const int idx = b * 768 + h;
  gate_f[idx] = fmaxf(gf + bfs[0], 0.f);
  colsum_tok[idx] = cs;
  colsumsq_tok[idx] = cq;
  colsum_tsg[idx] = tg;
}

// per-batch scalar stats for TSGSA and FSGSA. st: [tsg_s|tsg_q|fsg_s|fsg_q]x32
__global__ __launch_bounds__(256) void batch_stats_k(
    const float* __restrict__ gate_t, const float* __restrict__ rowsum,
    const float* __restrict__ rowsumsq, const float* __restrict__ gate_f,
    const float* __restrict__ colsum_tok, const float* __restrict__ colsumsq_tok,
    float* __restrict__ st) {
  __shared__ float red[4][256];
  const int b = blockIdx.x, tid = threadIdx.x;
  float ts = 0.f, tq = 0.f, fs = 0.f, fq = 0.f;
  for (int s = tid; s < 512; s += 256) {
    float g = gate_t[b * 512 + s];
    ts += g * rowsum[b * 512 + s];
    tq += g * g * rowsumsq[b * 512 + s];
  }
  for (int h = tid; h < 768; h += 256) {
    float g = gate_f[b * 768 + h];
    fs += g * colsum_tok[b * 768 + h];
    fq += g * g * colsumsq_tok[b * 768 + h];
  }
  red[0][tid] = ts; red[1][tid] = tq; red[2][tid] = fs; red[3][tid] = fq;
  __syncthreads();
  for (int o = 128; o > 0; o >>= 1) {
    if (tid < o) {
      red[0][tid] += red[0][tid + o];
      red[1][tid] += red[1][tid + o];
      red[2][tid] += red[2][tid + o];
      red[3][tid] += red[3][tid + o];
    }
    __syncthreads();
  }
  if (tid == 0) {
    st[b] = red[0][0]; st[32 + b] = red[1][0];
    st[64 + b] = red[2][0]; st[96 + b] = red[3][0];
  }
}

// build pooled [B, 7*768] from column sums + batch stats
__global__ __launch_bounds__(768) void pooled_k(
    const float* __restrict__ colsum_tok, const float* __restrict__ colsum_tsa,
    const float* __restrict__ bstat_tsa, const float* __restrict__ colsum_fsa,
    const float* __restrict__ bstat_fsa, const float* __restrict__ colsum_tgsa,
    const float* __restrict__ bstat_tgsa, const float* __restrict__ colsum_tsg,
    const float* __restrict__ gate_f, const float* __restrict__ st,
    float* __restrict__ pooled) {
  const int b = blockIdx.x, h = threadIdx.x;
  const float invS = 1.f / 512.f, invN = 1.f / (512.f * 768.f);
  const int i = b * 768 + h;
  float* pr = pooled + (size_t)b * 5376;
  pr[h] = colsum_tok[i] * invS;
  auto lnslot = [&](int slot, float cs, float bs, float bq) {
    float m = bs * invN;
    float var = bq * invN - m * m;
    pr[slot * 768 + h] = (cs * invS - m) * rsqrtf(var + 1e-8f);
  };
  lnslot(1, colsum_tsa[i], bstat_tsa[b], bstat_tsa[32 + b]);
  lnslot(2, colsum_fsa[i], bstat_fsa[b], bstat_fsa[32 + b]);
  lnslot(3, colsum_tgsa[i], bstat_tgsa[b], bstat_tgsa[32 + b]);
  const float fsg_cs = gate_f[i] * colsum_tok[i];
  lnslot(4, fsg_cs, st[64 + b], st[96 + b]);
  lnslot(5, colsum_tsg[i], st[b], st[32 + b]);
  lnslot(6, fsg_cs, st[64 + b], st[96 + b]);
}

// tmp1 += pooled-slice . W1-slice.  grid (6 colchunks, 42 kchunks), 256 thr.
__global__ __launch_bounds__(256) void fnn1_k(const float* __restrict__ pooled,
                                              const float* __restrict__ W1,
                                              float* __restrict__ tmp1) {
  __shared__ float sp[128][36];
  const int c0 = blockIdx.x << 7, k0 = blockIdx.y << 7;
  const int tid = threadIdx.x;
  for (int i = tid; i < 4096; i += 256) {
    int b = i >> 7, j = i & 127;
    sp[j][b] = pooled[(size_t)b * 5376 + k0 + j];
  }
  __syncthreads();
  const int c = c0 + (tid & 127);
  const int u = (tid >> 7) << 4;
  float acc[16];
#pragma unroll
  for (int t = 0; t < 16; ++t) acc[t] = 0.f;
#pragma unroll 4
  for (int j = 0; j < 128; ++j) {
    float w = W1[(size_t)(k0 + j) * 768 + c];
    const f32x4* row = (const f32x4*)&sp[j][u];
#pragma unroll
    for (int t4 = 0; t4 < 4; ++t4) {
      f32x4 v = row[t4];
#pragma unroll
      for (int r = 0; r < 4; ++r) acc[t4 * 4 + r] += v[r] * w;
    }
  }
#pragma unroll
  for (int t = 0; t < 16; ++t) atomicAdd(&tmp1[(u + t) * 768 + c], acc[t]);
}

// out[b,c] = sum_k (tmp1[b,k]+b1[k]) * W2[k,c] + b2[c].  One wave per output.
__global__ __launch_bounds__(256) void fnn2_k(const float* __restrict__ tmp1,
                                              const float* __restrict__ b1,
                                              const float* __restrict__ W2,
                                              const float* __restrict__ b2,
                                              float* __restrict__ out) {
  const int gw = blockIdx.x * 4 + (threadIdx.x >> 6);
  const int lane = threadIdx.x & 63;
  const int b = gw / 3, c = gw % 3;
  float a = 0.f;
#pragma unroll
  for (int i = 0; i < 12; ++i) {
    int k = lane + i * 64;
    a += (tmp1[b * 768 + k] + b1[k]) * W2[k * 3 + c];
  }
#pragma unroll
  for (int o = 32; o > 0; o >>= 1) a += __shfl_xor(a, o);
  if (lane == 0) out[b * 3 + c] = a + b2[c];
}

extern "C" void kernel_launch(void* const* d_in, const int* in_sizes, int n_in,
                              void* d_out, int out_size, void* d_ws, size_t ws_size,
                              hipStream_t stream) {
  const float* tokens = (const float*)d_in[0];
  const float* Wq = (const float*)d_in[1];
  const float* bq = (const float*)d_in[2];
  const float* Wk = (const float*)d_in[3];
  const float* bk = (const float*)d_in[4];
  const float* Wv = (const float*)d_in[5];
  const float* bv = (const float*)d_in[6];
  const float* Wts = (const float*)d_in[7];
  const float* bts = (const float*)d_in[8];
  const float* Wfs = (const float*)d_in[9];
  const float* bfs = (const float*)d_in[10];
  const float* Wtg = (const float*)d_in[11];
  const float* btg = (const float*)d_in[12];
  const float* W1 = (const float*)d_in[13];
  const float* b1 = (const float*)d_in[14];
  const float* W2 = (const float*)d_in[15];
  const float* b2 = (const float*)d_in[16];
  float* out = (float*)d_out;

  char* ws = (char*)d_ws;
  size_t off = 0;
  auto take = [&](size_t bytes) -> char* {
    char* p = ws + off;
    off += (bytes + 255) & ~(size_t)255;
    return p;
  };
  u16* tokb = (u16*)take((size_t)16384 * 768 * 2);
  u16* WqT = (u16*)take((size_t)768 * 768 * 2);  // WqT/WkT/WvT contiguous
  u16* WkT = (u16*)take((size_t)768 * 768 * 2);
  u16* WvT = (u16*)take((size_t)768 * 768 * 2);
  u16* WtgT = (u16*)take((size_t)768 * 768 * 2);
  u16* Qb = (u16*)take((size_t)16384 * 768 * 2);  // Qb/Kb/Vb contiguous
  u16* Kb = (u16*)take((size_t)16384 * 768 * 2);
  u16* Vb = (u16*)take((size_t)16384 * 768 * 2);
  u16* Qt = (u16*)take((size_t)768 * 16384 * 2);  // Qt/Kt/Vt contiguous
  u16* Kt = (u16*)take((size_t)768 * 16384 * 2);
  u16* Vt = (u16*)take((size_t)768 * 16384 * 2);
  u16* attb = (u16*)take((size_t)32 * 512 * 512 * 2);
  u16* attNt = (u16*)take((size_t)32 * 768 * 768 * 2);  // attN^T [b][g][h]
  float* bias3 = (float*)take(2304 * 4);
  // --- zeroed (atomic-accumulated) region: keep contiguous ---
  char* zbase = ws + off;
  float* colsum_tsa = (float*)take(24576 * 4);
  float* colsum_fsa = (float*)take(24576 * 4);
  float* colsum_tgsa = (float*)take(24576 * 4);
  float* bstat_tsa = (float*)take(64 * 4);
  float* bstat_fsa = (float*)take(64 * 4);
  float* bstat_tgsa = (float*)take(64 * 4);
  float* tmp1 = (float*)take((size_t)32 * 768 * 4);
  size_t zbytes = (size_t)((ws + off) - zbase);
  // --- fully-overwritten buffers ---
  float* colsum_tsg = (float*)take(24576 * 4);
  float* gate_t = (float*)take(16384 * 4);
  float* rowsum = (float*)take(16384 * 4);
  float* rowsumsq = (float*)take(16384 * 4);
  float* gate_f = (float*)take(24576 * 4);
  float* colsum_tok = (float*)take(24576 * 4);
  float* colsumsq_tok = (float*)take(24576 * 4);
  float* st4 = (float*)take(128 * 4);
  float* pooled = (float*)take((size_t)32 * 5376 * 4);

  hipMemsetAsync(zbase, 0, zbytes, stream);
  hipMemcpyAsync(bias3, bq, 768 * 4, hipMemcpyDeviceToDevice, stream);
  hipMemcpyAsync(bias3 + 768, bk, 768 * 4, hipMemcpyDeviceToDevice, stream);
  hipMemcpyAsync(bias3 + 1536, bv, 768 * 4, hipMemcpyDeviceToDevice, stream);

  const float scale = 1.0f / sqrtf(768.0f);
  const dim3 blk(256);
  const dim3 blk512(512);

  // prep: tokens->bf16 + row stats (fused); weights->transposed bf16
  cvt_row_k<<<4096, blk, 0, stream>>>(tokens, tokb, Wts, bts, gate_t, rowsum,
                                      rowsumsq);
  transpose_w_k<<<dim3(12, 12), blk, 0, stream>>>(Wq, WqT);
  transpose_w_k<<<dim3(12, 12), blk, 0, stream>>>(Wk, WkT);
  transpose_w_k<<<dim3(12, 12), blk, 0, stream>>>(Wv, WvT);
  transpose_w_k<<<dim3(12, 12), blk, 0, stream>>>(Wtg, WtgT);

  // fused Q|K|V projection: N=2304 (B panel 3.5MB fits per-XCD L2), BM=256
  gemm_f_k<0><<<dim3(18, 64, 1), blk512, 0, stream>>>(
      tokb, WqT, Qb, Qt, bias3, nullptr, nullptr, nullptr, 768, 768, 768, 768,
      0, 0, 12582912, 0.f);
  // TGSA (gated reduce), reads tokb
  gemm_f_k<1><<<dim3(6, 64, 1), blk512, 0, stream>>>(
      tokb, WtgT, nullptr, nullptr, btg, tokb, colsum_tgsa, bstat_tgsa, 768,
      768, 768, 0, 0, 0, 0, 0.f);

  // attN^T directly: attNt[g][h] = sum_s Kt[g][s] Qt[h][s]  (operand swap)
  gemm_f_k<2><<<dim3(6, 3, 32), blk512, 0, stream>>>(
      Kt, Qt, attNt, nullptr, nullptr, nullptr, nullptr, nullptr, 512, 16384,
      16384, 768, 512, 512, 589824, scale);
  colsoftmax_k<<<dim3(32, 12), blk, 0, stream>>>(attNt);

  // token attention scores: att[s,t] = Q[s,:].K[t,:] * scale
  gemm_f_k<2><<<dim3(4, 2, 32), blk512, 0, stream>>>(
      Qb, Kb, attb, nullptr, nullptr, nullptr, nullptr, nullptr, 768, 768, 768,
      512, 393216, 393216, 262144, scale);
  softmax_k<512><<<16384, 256, 0, stream>>>(attb);

  // TSA = att @ V  -> reduce only
  gemm_f_k<3><<<dim3(6, 2, 32), blk512, 0, stream>>>(
      attb, Vt, nullptr, nullptr, nullptr, nullptr, colsum_tsa, bstat_tsa, 512,
      512, 16384, 0, 262144, 512, 0, 0.f);
  // FSA = V @ attN -> reduce only  (B rows = attNt rows g)
  gemm_f_k<3><<<dim3(6, 2, 32), blk512, 0, stream>>>(
      Vb, attNt, nullptr, nullptr, nullptr, nullptr, colsum_fsa, bstat_fsa, 768,
      768, 768, 0, 393216, 589824, 0, 0.f);

  // remaining gate-branch statistics
  col_stats_k<<<dim3(32, 3), blk, 0, stream>>>(tokb, Wfs, bfs, gate_t, gate_f,
                                               colsum_tok, colsumsq_tok, colsum_tsg);
  batch_stats_k<<<32, blk, 0, stream>>>(gate_t, rowsum, rowsumsq, gate_f,
                                        colsum_tok, colsumsq_tok, st4);

  pooled_k<<<32, 768, 0, stream>>>(colsum_tok, colsum_tsa, bstat_tsa, colsum_fsa,
                                   bstat_fsa, colsum_tgsa, bstat_tgsa, colsum_tsg,
                                   gate_f, st4, pooled);
  fnn1_k<<<dim3(6, 42), blk, 0, stream>>>(pooled, W1, tmp1);
  fnn2_k<<<24, blk, 0, stream>>>(tmp1, b1, W2, b2, out);
}

// Round 10
// 418.801 us; speedup vs baseline: 2.0555x; 1.0464x over previous
//
#include <hip/hip_runtime.h>
#include <cmath>

typedef unsigned short u16;
typedef __attribute__((ext_vector_type(4))) float f32x4;
typedef __attribute__((ext_vector_type(4))) unsigned int u32x4;
typedef __attribute__((ext_vector_type(8))) __bf16 bf16x8;

__device__ __forceinline__ u16 f2b(float f) {
  unsigned int u = __builtin_bit_cast(unsigned int, f);
  return (u16)((u + 0x7fffu + ((u >> 16) & 1u)) >> 16);  // RNE
}
__device__ __forceinline__ float b2f(u16 h) {
  unsigned int u = ((unsigned int)h) << 16;
  return __builtin_bit_cast(float, u);
}

__device__ __forceinline__ void glds16(const u16* g, u16* l) {
  __builtin_amdgcn_global_load_lds(
      (const __attribute__((address_space(1))) void*)g,
      (__attribute__((address_space(3))) void*)l, 16, 0, 0);
}

// ---------------------------------------------------------------------------
// Fast bf16-MFMA GEMM, 256x128 tile, BK=32, 512 threads (8 waves, 4x2).
// A: M x K row-major bf16 (lda), per-z stride sA; B: N x K row-major (ldb).
// global_load_lds w16, double-buffered, counted vmcnt(3), chunk swizzle on
// both global-src and ds_read sides. Bijective XCD remap (nwg % 8 == 0).
// Stores through L2 (no nontemporal - r7 lesson).
// EPI 0: fused QKV (N=2304): C row-major [16384][768] + C^T BATCH-LOCAL
//        [z][768][512] packed 8B (1KB col stride -> tight L2 write window).
// EPI 1: TGSA reduce: v = sigmoid(acc+bias[n]) * tokb[m,n]; colsum/bsum/bsumsq
// EPI 2: store bf16 (acc*scale)   (token-attention scores)
// EPI 3: reduce-only: colsum[z,n], bsum[z], bsumsq[z]
// EPI 4: scores + per-tile column softmax partials (pmax/psum [z][3][768])
//        for the feature-attention column softmax (attN^T, softmax over m).
// ---------------------------------------------------------------------------
template <int EPI>
__global__ __launch_bounds__(512) void gemm_f_k(
    const u16* __restrict__ Ap, const u16* __restrict__ Bp, u16* __restrict__ Cp,
    u16* __restrict__ CpT, const float* __restrict__ bias,
    const u16* __restrict__ tokp, float* __restrict__ colsum,
    float* __restrict__ bstat, int K, int lda, int ldb, int ldc, long sA,
    long sB, long sC, float scale) {
  __shared__ alignas(16) u16 Asm[2][8192];  // 256 rows x 32 u16, dbuf
  __shared__ alignas(16) u16 Bsm[2][4096];  // 128 rows x 32 u16, dbuf
  __shared__ float scol_s[128];
  __shared__ float sred[2];

  // bijective XCD-chunked remap (nwg % 8 == 0 for all our grids)
  const int gx = gridDim.x, gxy = gx * gridDim.y;
  const int nwg = gxy * gridDim.z;
  int orig = (blockIdx.z * gridDim.y + blockIdx.y) * gx + blockIdx.x;
  int gwi = (orig & 7) * (nwg >> 3) + (orig >> 3);
  const int z = gwi / gxy;
  int rem = gwi - z * gxy;
  const int ty = rem / gx, tx = rem - ty * gx;
  const int tileM = ty << 8, tileN = tx << 7;

  const u16* Abase = Ap + (size_t)z * sA;
  const u16* Bbase = Bp + (size_t)z * sB;

  const int tid = threadIdx.x;
  const int lane = tid & 63, w = tid >> 6;          // w in [0,8)
  const int wr = (w >> 1) << 6, wc = (w & 1) << 6;  // 4 row-waves x 2 col-waves
  const int fr = lane & 15, fg = lane >> 4;

  f32x4 acc[4][4];
#pragma unroll
  for (int i = 0; i < 4; ++i)
#pragma unroll
    for (int j = 0; j < 4; ++j) acc[i][j] = (f32x4){0.f, 0.f, 0.f, 0.f};

  // staging: wave w covers A rows [w*32,w*32+32) and B rows [w*16,w*16+16).
  const int sArow = (w << 5) + (lane >> 2);
  const int sBrow = (w << 4) + (lane >> 2);
  const int scol = (((lane & 3) ^ ((lane >> 3) & 3)) << 3);
  const u16* gA = Abase + (size_t)(tileM + sArow) * lda + scol;
  const u16* gB = Bbase + (size_t)(tileN + sBrow) * ldb + scol;
  const int ldsA = (w << 5) * 32;
  const int ldsB = (w << 4) * 32;

  auto STAGE = [&](int buf, int k0) {
    glds16(gA + k0, &Asm[buf][ldsA]);
    glds16(gA + (size_t)16 * lda + k0, &Asm[buf][ldsA + 512]);
    glds16(gB + k0, &Bsm[buf][ldsB]);
  };

  const int col_off = ((fg ^ ((fr >> 1) & 3)) << 3);

  const int nt = K >> 5;
  STAGE(0, 0);
  int cur = 0;
  for (int t = 0; t < nt; ++t) {
    if (t + 1 < nt) {
      STAGE(cur ^ 1, (t + 1) << 5);
      asm volatile("s_waitcnt vmcnt(3)" ::: "memory");
    } else {
      asm volatile("s_waitcnt vmcnt(0)" ::: "memory");
    }
    __builtin_amdgcn_s_barrier();
    asm volatile("" ::: "memory");
    const u16* Ab = Asm[cur];
    const u16* Bb = Bsm[cur];
    bf16x8 av[4], bw[4];
#pragma unroll
    for (int m = 0; m < 4; ++m)
      av[m] = *(const bf16x8*)&Ab[(wr + (m << 4) + fr) * 32 + col_off];
#pragma unroll
    for (int n = 0; n < 4; ++n)
      bw[n] = *(const bf16x8*)&Bb[(wc + (n << 4) + fr) * 32 + col_off];
#pragma unroll
    for (int m = 0; m < 4; ++m)
#pragma unroll
      for (int n = 0; n < 4; ++n)
        acc[m][n] =
            __builtin_amdgcn_mfma_f32_16x16x32_bf16(av[m], bw[n], acc[m][n], 0, 0, 0);
    asm volatile("" ::: "memory");
    __builtin_amdgcn_s_barrier();
    cur ^= 1;
  }

  // ---- epilogue ----
  if constexpr (EPI == 0) {
    const int cbuf = tileN / 768;
    const int nbase = tileN - cbuf * 768;
    u16* Cz = Cp + (size_t)cbuf * sC;
#pragma unroll
    for (int m = 0; m < 4; ++m) {
#pragma unroll
      for (int n = 0; n < 4; ++n) {
        const int gcol = tileN + wc + (n << 4) + fr;
        const int lcol = nbase + wc + (n << 4) + fr;
        const float bv2 = bias[gcol];
#pragma unroll
        for (int r = 0; r < 4; ++r) {
          const int grow = tileM + wr + (m << 4) + (fg << 2) + r;
          Cz[(size_t)grow * 768 + lcol] = f2b(acc[m][n][r] + bv2);
        }
      }
    }
    // transposed store: batch-local [z][768][512] (1KB column stride)
    u16* Ct = CpT + (size_t)cbuf * sC;
    const int zb = tileM >> 9;
    const int sbase = tileM & 511;
#pragma unroll
    for (int m = 0; m < 4; ++m) {
#pragma unroll
      for (int n = 0; n < 4; ++n) {
        const int gcol = tileN + wc + (n << 4) + fr;
        const int lcol = nbase + wc + (n << 4) + fr;
        const int srow0 = sbase + wr + (m << 4) + (fg << 2);
        union { u16 u[4]; unsigned long long q; } pk;
#pragma unroll
        for (int r = 0; r < 4; ++r) pk.u[r] = f2b(acc[m][n][r] + bias[gcol]);
        *(unsigned long long*)&Ct[((size_t)(zb * 768 + lcol) << 9) + srow0] = pk.q;
      }
    }
  } else if constexpr (EPI == 1) {
    // TGSA: v = sigmoid(acc + btg[n]) * tokb[m,n]
    if (tid < 128) scol_s[tid] = 0.f;
    if (tid == 0) { sred[0] = 0.f; sred[1] = 0.f; }
    __syncthreads();
    float ls = 0.f, lq = 0.f;
#pragma unroll
    for (int n = 0; n < 4; ++n) {
      float cpart = 0.f;
      const int gcol = tileN + wc + (n << 4) + fr;
      const float bv2 = bias[gcol];
#pragma unroll
      for (int m = 0; m < 4; ++m) {
#pragma unroll
        for (int r = 0; r < 4; ++r) {
          const int grow = tileM + wr + (m << 4) + (fg << 2) + r;
          float g = 1.f / (1.f + __expf(-(acc[m][n][r] + bv2)));
          float v = g * b2f(tokp[(size_t)grow * 768 + gcol]);
          cpart += v; ls += v; lq += v * v;
        }
      }
      atomicAdd(&scol_s[wc + (n << 4) + fr], cpart);
    }
    atomicAdd(&sred[0], ls);
    atomicAdd(&sred[1], lq);
    __syncthreads();
    const int b = tileM >> 9;
    if (tid < 128) atomicAdd(&colsum[(size_t)b * 768 + tileN + tid], scol_s[tid]);
    if (tid == 0) {
      atomicAdd(&bstat[b], sred[0]);
      atomicAdd(&bstat[32 + b], sred[1]);
    }
  } else if constexpr (EPI == 2) {
    u16* Cz = Cp + (size_t)z * sC;
#pragma unroll
    for (int m = 0; m < 4; ++m) {
#pragma unroll
      for (int n = 0; n < 4; ++n) {
        const int gcol = tileN + wc + (n << 4) + fr;
#pragma unroll
        for (int r = 0; r < 4; ++r) {
          const int grow = tileM + wr + (m << 4) + (fg << 2) + r;
          Cz[(size_t)grow * ldc + gcol] = f2b(acc[m][n][r] * scale);
        }
      }
    }
  } else if constexpr (EPI == 4) {
    // scores + per-tile column max / sum-exp partials (softmax over m dim)
    u16* Cz = Cp + (size_t)z * sC;
    float lmax[4];
#pragma unroll
    for (int n = 0; n < 4; ++n) {
      const int gcol = tileN + wc + (n << 4) + fr;
      float mx = -1e30f;
#pragma unroll
      for (int m = 0; m < 4; ++m) {
#pragma unroll
        for (int r = 0; r < 4; ++r) {
          const int grow = tileM + wr + (m << 4) + (fg << 2) + r;
          float v = acc[m][n][r] * scale;
          Cz[(size_t)grow * ldc + gcol] = f2b(v);
          mx = fmaxf(mx, v);
        }
      }
      lmax[n] = mx;
    }
    float* red = (float*)&Asm[0][0];  // [16 slots][132] conflict-free
    const int slot = ((w >> 1) << 2) + fg;
    __syncthreads();
#pragma unroll
    for (int n = 0; n < 4; ++n)
      red[slot * 132 + wc + (n << 4) + fr] = lmax[n];
    __syncthreads();
    if (tid < 128) {
      float m2 = red[tid];
#pragma unroll
      for (int i = 1; i < 16; ++i) m2 = fmaxf(m2, red[i * 132 + tid]);
      scol_s[tid] = m2;
    }
    __syncthreads();
    float lsum[4];
#pragma unroll
    for (int n = 0; n < 4; ++n) {
      const float M = scol_s[wc + (n << 4) + fr];
      float s2 = 0.f;
#pragma unroll
      for (int m = 0; m < 4; ++m)
#pragma unroll
        for (int r = 0; r < 4; ++r) s2 += __expf(acc[m][n][r] * scale - M);
      lsum[n] = s2;
    }
    __syncthreads();
#pragma unroll
    for (int n = 0; n < 4; ++n)
      red[slot * 132 + wc + (n << 4) + fr] = lsum[n];
    __syncthreads();
    if (tid < 128) {
      float s2 = 0.f;
#pragma unroll
      for (int i = 0; i < 16; ++i) s2 += red[i * 132 + tid];
      const int ty3 = tileM >> 8;  // 0..2
      const size_t pidx = ((size_t)z * 3 + ty3) * 768 + tileN + tid;
      colsum[pidx] = scol_s[tid];  // pmax
      bstat[pidx] = s2;            // psum
    }
  } else {
    if (tid < 128) scol_s[tid] = 0.f;
    if (tid == 0) { sred[0] = 0.f; sred[1] = 0.f; }
    __syncthreads();
    float ls = 0.f, lq = 0.f;
#pragma unroll
    for (int n = 0; n < 4; ++n) {
      float cpart = 0.f;
#pragma unroll
      for (int m = 0; m < 4; ++m) {
#pragma unroll
        for (int r = 0; r < 4; ++r) {
          float v = acc[m][n][r];
          cpart += v; ls += v; lq += v * v;
        }
      }
      atomicAdd(&scol_s[wc + (n << 4) + fr], cpart);
    }
    atomicAdd(&sred[0], ls);
    atomicAdd(&sred[1], lq);
    __syncthreads();
    if (tid < 128) atomicAdd(&colsum[(size_t)z * 768 + tileN + tid], scol_s[tid]);
    if (tid == 0) {
      atomicAdd(&bstat[z], sred[0]);
      atomicAdd(&bstat[32 + z], sred[1]);
    }
  }
}

// fused: tokens f32 -> tokb bf16 + per-row gate_t/rowsum/rowsumsq. 1 wave/row.
__global__ __launch_bounds__(256) void cvt_row_k(
    const float* __restrict__ tok, u16* __restrict__ tokb,
    const float* __restrict__ Wts, const float* __restrict__ bts,
    float* __restrict__ gate_t, float* __restrict__ rowsum,
    float* __restrict__ rowsumsq) {
  const int w = threadIdx.x >> 6, lane = threadIdx.x & 63;
  const int row = blockIdx.x * 4 + w;
  const float* p = tok + (size_t)row * 768;
  u16* q = tokb + (size_t)row * 768;
  float s = 0.f, sq = 0.f, g = 0.f;
#pragma unroll
  for (int i = 0; i < 3; ++i) {
    const int idx = (i * 64 + lane) << 2;
    f32x4 v = *(const f32x4*)(p + idx);
    f32x4 wv = *(const f32x4*)(Wts + idx);
    union { u16 u[4]; unsigned long long q8; } pk;
#pragma unroll
    for (int j = 0; j < 4; ++j) {
      s += v[j]; sq += v[j] * v[j]; g += v[j] * wv[j];
      pk.u[j] = f2b(v[j]);
    }
    *(unsigned long long*)(q + idx) = pk.q8;
  }
#pragma unroll
  for (int o = 32; o > 0; o >>= 1) {
    s += __shfl_xor(s, o); sq += __shfl_xor(sq, o); g += __shfl_xor(g, o);
  }
  if (lane == 0) {
    gate_t[row] = fmaxf(g + bts[0], 0.f);
    rowsum[row] = s;
    rowsumsq[row] = sq;
  }
}

// W [768][768] f32 -> WT [768][768] bf16 (transposed)
__global__ __launch_bounds__(256) void transpose_w_k(const float* __restrict__ W,
                                                     u16* __restrict__ WT) {
  __shared__ float t[64][65];
  const int r0 = blockIdx.y << 6, c0 = blockIdx.x << 6;
  for (int i = threadIdx.x; i < 4096; i += 256) {
    int r = i >> 6, c = i & 63;
    t[r][c] = W[(size_t)(r0 + r) * 768 + c0 + c];
  }
  __syncthreads();
  for (int i = threadIdx.x; i < 4096; i += 256) {
    int rr = i >> 6, cc = i & 63;
    WT[(size_t)(c0 + rr) * 768 + r0 + cc] = f2b(t[cc][rr]);
  }
}

// in-place row softmax on bf16 scores; block=256, grid=numRows
template <int LEN>
__global__ __launch_bounds__(256) void softmax_k(u16* __restrict__ data) {
  constexpr int NP = LEN / 256;
  const int row = blockIdx.x, tid = threadIdx.x;
  u16* p = data + (size_t)row * LEN;
  const int lane = tid & 63, wid = tid >> 6;
  float v[NP];
  float mx = -1e30f;
#pragma unroll
  for (int i = 0; i < NP; ++i) { v[i] = b2f(p[tid + (i << 8)]); mx = fmaxf(mx, v[i]); }
#pragma unroll
  for (int o = 32; o > 0; o >>= 1) mx = fmaxf(mx, __shfl_xor(mx, o));
  __shared__ float red[4], red2[4];
  if (lane == 0) red[wid] = mx;
  __syncthreads();
  mx = fmaxf(fmaxf(red[0], red[1]), fmaxf(red[2], red[3]));
  float sum = 0.f;
#pragma unroll
  for (int i = 0; i < NP; ++i) { v[i] = __expf(v[i] - mx); sum += v[i]; }
#pragma unroll
  for (int o = 32; o > 0; o >>= 1) sum += __shfl_xor(sum, o);
  if (lane == 0) red2[wid] = sum;
  __syncthreads();
  sum = red2[0] + red2[1] + red2[2] + red2[3];
  const float inv = 1.f / sum;
#pragma unroll
  for (int i = 0; i < NP; ++i) p[tid + (i << 8)] = f2b(v[i] * inv);
}

// single-pass column normalize on attNt [32][768 g][768 h] using GEMM-epilogue
// partials: M = max_ty pmax, S = sum_ty psum*exp(pmax-M).
__global__ __launch_bounds__(256) void colnorm_k(u16* __restrict__ data,
                                                 const float* __restrict__ pmax,
                                                 const float* __restrict__ psum) {
  __shared__ u16 tile[32][72];
  const int tid = threadIdx.x;
  const int b = blockIdx.x;
  u16* base = data + (size_t)b * 589824 + (blockIdx.y << 6);
  const int lr = tid >> 3, seg = (tid & 7) << 3;
  const int c = tid & 63, q = tid >> 6;
  const size_t p0 = (size_t)b * 3 * 768 + (blockIdx.y << 6) + c;
  const float m0 = pmax[p0], m1 = pmax[p0 + 768], m2 = pmax[p0 + 1536];
  const float M = fmaxf(fmaxf(m0, m1), m2);
  const float S = psum[p0] * __expf(m0 - M) + psum[p0 + 768] * __expf(m1 - M) +
                  psum[p0 + 1536] * __expf(m2 - M);
  const float inv = 1.f / S;
  for (int ch = 0; ch < 24; ++ch) {
    u16* g = base + (size_t)(ch * 32 + lr) * 768 + seg;
    *(u32x4*)&tile[lr][seg] = *(const u32x4*)g;
    __syncthreads();
#pragma unroll
    for (int i = 0; i < 8; ++i) {
      const int r = (q << 3) + i;
      tile[r][c] = f2b(__expf(b2f(tile[r][c]) - M) * inv);
    }
    __syncthreads();
    *(u32x4*)g = *(const u32x4*)&tile[lr][seg];
    __syncthreads();
  }
}

// per-column stats from tokb: gate_f, colsum_tok, colsumsq_tok, colsum_tsgsa.
__global__ __launch_bounds__(256) void col_stats_k(
    const u16* __restrict__ tokb, const float* __restrict__ Wfs,
    const float* __restrict__ bfs, const float* __restrict__ gate_t,
    float* __restrict__ gate_f, float* __restrict__ colsum_tok,
    float* __restrict__ colsumsq_tok, float* __restrict__ colsum_tsg) {
  const int b = blockIdx.x, h = blockIdx.y * 256 + threadIdx.x;
  const u16* p = tokb + (size_t)b * 512 * 768 + h;
  const float* gt = gate_t + b * 512;
  float cs = 0.f, cq = 0.f, gf = 0.f, tg = 0.f;
#pragma unroll 4
  for (int s = 0; s < 512; ++s) {
    float t = b2f(p[(size_t)s * 768]);
    cs += t; cq += t * t; gf += t * Wfs[s]; tg += t * gt[s];
  }
  const int idx = b * 768 + h;
  gate_f[idx] = fmaxf(gf + bfs[0], 0.f);
  colsum_tok[idx] = cs;
  colsumsq_tok[idx] = cq;
  colsum_tsg[idx] = tg;
}

// per-batch scalar stats for TSGSA and FSGSA. st: [tsg_s|tsg_q|fsg_s|fsg_q]x32
__global__ __launch_bounds__(256) void batch_stats_k(
    const float* __restrict__ gate_t, const float* __restrict__ rowsum,
    const float* __restrict__ rowsumsq, const float* __restrict__ gate_f,
    const float* __restrict__ colsum_tok, const float* __restrict__ colsumsq_tok,
    float* __restrict__ st) {
  __shared__ float red[4][256];
  const int b = blockIdx.x, tid = threadIdx.x;
  float ts = 0.f, tq = 0.f, fs = 0.f, fq = 0.f;
  for (int s = tid; s < 512; s += 256) {
    float g = gate_t[b * 512 + s];
    ts += g * rowsum[b * 512 + s];
    tq += g * g * rowsumsq[b * 512 + s];
  }
  for (int h = tid; h < 768; h += 256) {
    float g = gate_f[b * 768 + h];
    fs += g * colsum_tok[b * 768 + h];
    fq += g * g * colsumsq_tok[b * 768 + h];
  }
  red[0][tid] = ts; red[1][tid] = tq; red[2][tid] = fs; red[3][tid] = fq;
  __syncthreads();
  for (int o = 128; o > 0; o >>= 1) {
    if (tid < o) {
      red[0][tid] += red[0][tid + o];
      red[1][tid] += red[1][tid + o];
      red[2][tid] += red[2][tid + o];
      red[3][tid] += red[3][tid + o];
    }
    __syncthreads();
  }
  if (tid == 0) {
    st[b] = red[0][0]; st[32 + b] = red[1][0];
    st[64 + b] = red[2][0]; st[96 + b] = red[3][0];
  }
}

// build pooled [B, 7*768] from column sums + batch stats
__global__ __launch_bounds__(768) void pooled_k(
    const float* __restrict__ colsum_tok, const float* __restrict__ colsum_tsa,
    const float* __restrict__ bstat_tsa, const float* __restrict__ colsum_fsa,
    const float* __restrict__ bstat_fsa, const float* __restrict__ colsum_tgsa,
    const float* __restrict__ bstat_tgsa, const float* __restrict__ colsum_tsg,
    const float* __restrict__ gate_f, const float* __restrict__ st,
    float* __restrict__ pooled) {
  const int b = blockIdx.x, h = threadIdx.x;
  const float invS = 1.f / 512.f, invN = 1.f / (512.f * 768.f);
  const int i = b * 768 + h;
  float* pr = pooled + (size_t)b * 5376;
  pr[h] = colsum_tok[i] * invS;
  auto lnslot = [&](int slot, float cs, float bs, float bq) {
    float m = bs * invN;
    float var = bq * invN - m * m;
    pr[slot * 768 + h] = (cs * invS - m) * rsqrtf(var + 1e-8f);
  };
  lnslot(1, colsum_tsa[i], bstat_tsa[b], bstat_tsa[32 + b]);
  lnslot(2, colsum_fsa[i], bstat_fsa[b], bstat_fsa[32 + b]);
  lnslot(3, colsum_tgsa[i], bstat_tgsa[b], bstat_tgsa[32 + b]);
  const float fsg_cs = gate_f[i] * colsum_tok[i];
  lnslot(4, fsg_cs, st[64 + b], st[96 + b]);
  lnslot(5, colsum_tsg[i], st[b], st[32 + b]);
  lnslot(6, fsg_cs, st[64 + b], st[96 + b]);
}

// tmp1 += pooled-slice . W1-slice.  grid (6 colchunks, 42 kchunks), 256 thr.
__global__ __launch_bounds__(256) void fnn1_k(const float* __restrict__ pooled,
                                              const float* __restrict__ W1,
                                              float* __restrict__ tmp1) {
  __shared__ float sp[128][36];
  const int c0 = blockIdx.x << 7, k0 = blockIdx.y << 7;
  const int tid = threadIdx.x;
  for (int i = tid; i < 4096; i += 256) {
    int b = i >> 7, j = i & 127;
    sp[j][b] = pooled[(size_t)b * 5376 + k0 + j];
  }
  __syncthreads();
  const int c = c0 + (tid & 127);
  const int u = (tid >> 7) << 4;
  float acc[16];
#pragma unroll
  for (int t = 0; t < 16; ++t) acc[t] = 0.f;
#pragma unroll 4
  for (int j = 0; j < 128; ++j) {
    float w = W1[(size_t)(k0 + j) * 768 + c];
    const f32x4* row = (const f32x4*)&sp[j][u];
#pragma unroll
    for (int t4 = 0; t4 < 4; ++t4) {
      f32x4 v = row[t4];
#pragma unroll
      for (int r = 0; r < 4; ++r) acc[t4 * 4 + r] += v[r] * w;
    }
  }
#pragma unroll
  for (int t = 0; t < 16; ++t) atomicAdd(&tmp1[(u + t) * 768 + c], acc[t]);
}

// out[b,c] = sum_k (tmp1[b,k]+b1[k]) * W2[k,c] + b2[c].  One wave per output.
__global__ __launch_bounds__(256) void fnn2_k(const float* __restrict__ tmp1,
                                              const float* __restrict__ b1,
                                              const float* __restrict__ W2,
                                              const float* __restrict__ b2,
                                              float* __restrict__ out) {
  const int gw = blockIdx.x * 4 + (threadIdx.x >> 6);
  const int lane = threadIdx.x & 63;
  const int b = gw / 3, c = gw % 3;
  float a = 0.f;
#pragma unroll
  for (int i = 0; i < 12; ++i) {
    int k = lane + i * 64;
    a += (tmp1[b * 768 + k] + b1[k]) * W2[k * 3 + c];
  }
#pragma unroll
  for (int o = 32; o > 0; o >>= 1) a += __shfl_xor(a, o);
  if (lane == 0) out[b * 3 + c] = a + b2[c];
}

extern "C" void kernel_launch(void* const* d_in, const int* in_sizes, int n_in,
                              void* d_out, int out_size, void* d_ws, size_t ws_size,
                              hipStream_t stream) {
  const float* tokens = (const float*)d_in[0];
  const float* Wq = (const float*)d_in[1];
  const float* bq = (const float*)d_in[2];
  const float* Wk = (const float*)d_in[3];
  const float* bk = (const float*)d_in[4];
  const float* Wv = (const float*)d_in[5];
  const float* bv = (const float*)d_in[6];
  const float* Wts = (const float*)d_in[7];
  const float* bts = (const float*)d_in[8];
  const float* Wfs = (const float*)d_in[9];
  const float* bfs = (const float*)d_in[10];
  const float* Wtg = (const float*)d_in[11];
  const float* btg = (const float*)d_in[12];
  const float* W1 = (const float*)d_in[13];
  const float* b1 = (const float*)d_in[14];
  const float* W2 = (const float*)d_in[15];
  const float* b2 = (const float*)d_in[16];
  float* out = (float*)d_out;

  char* ws = (char*)d_ws;
  size_t off = 0;
  auto take = [&](size_t bytes) -> char* {
    char* p = ws + off;
    off += (bytes + 255) & ~(size_t)255;
    return p;
  };
  u16* tokb = (u16*)take((size_t)16384 * 768 * 2);
  u16* WqT = (u16*)take((size_t)768 * 768 * 2);  // WqT/WkT/WvT contiguous
  u16* WkT = (u16*)take((size_t)768 * 768 * 2);
  u16* WvT = (u16*)take((size_t)768 * 768 * 2);
  u16* WtgT = (u16*)take((size_t)768 * 768 * 2);
  u16* Qb = (u16*)take((size_t)16384 * 768 * 2);  // Qb/Kb/Vb contiguous
  u16* Kb = (u16*)take((size_t)16384 * 768 * 2);
  u16* Vb = (u16*)take((size_t)16384 * 768 * 2);
  u16* Qt = (u16*)take((size_t)32 * 768 * 512 * 2);  // batch-local [z][768][512]
  u16* Kt = (u16*)take((size_t)32 * 768 * 512 * 2);
  u16* Vt = (u16*)take((size_t)32 * 768 * 512 * 2);
  u16* attb = (u16*)take((size_t)32 * 512 * 512 * 2);
  u16* attNt = (u16*)take((size_t)32 * 768 * 768 * 2);  // attN^T [b][g][h]
  float* bias3 = (float*)take(2304 * 4);
  float* pmax = (float*)take((size_t)32 * 3 * 768 * 4);
  float* psum = (float*)take((size_t)32 * 3 * 768 * 4);
  // --- zeroed (atomic-accumulated) region: keep contiguous ---
  char* zbase = ws + off;
  float* colsum_tsa = (float*)take(24576 * 4);
  float* colsum_fsa = (float*)take(24576 * 4);
  float* colsum_tgsa = (float*)take(24576 * 4);
  float* bstat_tsa = (float*)take(64 * 4);
  float* bstat_fsa = (float*)take(64 * 4);
  float* bstat_tgsa = (float*)take(64 * 4);
  float* tmp1 = (float*)take((size_t)32 * 768 * 4);
  size_t zbytes = (size_t)((ws + off) - zbase);
  // --- fully-overwritten buffers ---
  float* colsum_tsg = (float*)take(24576 * 4);
  float* gate_t = (float*)take(16384 * 4);
  float* rowsum = (float*)take(16384 * 4);
  float* rowsumsq = (float*)take(16384 * 4);
  float* gate_f = (float*)take(24576 * 4);
  float* colsum_tok = (float*)take(24576 * 4);
  float* colsumsq_tok = (float*)take(24576 * 4);
  float* st4 = (float*)take(128 * 4);
  float* pooled = (float*)take((size_t)32 * 5376 * 4);

  hipMemsetAsync(zbase, 0, zbytes, stream);
  hipMemcpyAsync(bias3, bq, 768 * 4, hipMemcpyDeviceToDevice, stream);
  hipMemcpyAsync(bias3 + 768, bk, 768 * 4, hipMemcpyDeviceToDevice, stream);
  hipMemcpyAsync(bias3 + 1536, bv, 768 * 4, hipMemcpyDeviceToDevice, stream);

  const float scale = 1.0f / sqrtf(768.0f);
  const dim3 blk(256);
  const dim3 blk512(512);

  // prep: tokens->bf16 + row stats (fused); weights->transposed bf16
  cvt_row_k<<<4096, blk, 0, stream>>>(tokens, tokb, Wts, bts, gate_t, rowsum,
                                      rowsumsq);
  transpose_w_k<<<dim3(12, 12), blk, 0, stream>>>(Wq, WqT);
  transpose_w_k<<<dim3(12, 12), blk, 0, stream>>>(Wk, WkT);
  transpose_w_k<<<dim3(12, 12), blk, 0, stream>>>(Wv, WvT);
  transpose_w_k<<<dim3(12, 12), blk, 0, stream>>>(Wtg, WtgT);

  // fused Q|K|V projection: N=2304, BM=256, batch-local transposed outputs
  gemm_f_k<0><<<dim3(18, 64, 1), blk512, 0, stream>>>(
      tokb, WqT, Qb, Qt, bias3, nullptr, nullptr, nullptr, 768, 768, 768, 768,
      0, 0, 12582912, 0.f);
  // TGSA (gated reduce), reads tokb
  gemm_f_k<1><<<dim3(6, 64, 1), blk512, 0, stream>>>(
      tokb, WtgT, nullptr, nullptr, btg, tokb, colsum_tgsa, bstat_tgsa, 768,
      768, 768, 0, 0, 0, 0, 0.f);

  // attN^T + column-softmax partials: attNt[g][h] = sum_s Kt[g][s] Qt[h][s]
  gemm_f_k<4><<<dim3(6, 3, 32), blk512, 0, stream>>>(
      Kt, Qt, attNt, nullptr, nullptr, nullptr, pmax, psum, 512, 512, 512, 768,
      393216, 393216, 589824, scale);
  colnorm_k<<<dim3(32, 12), blk, 0, stream>>>(attNt, pmax, psum);

  // token attention scores: att[s,t] = Q[s,:].K[t,:] * scale
  gemm_f_k<2><<<dim3(4, 2, 32), blk512, 0, stream>>>(
      Qb, Kb, attb, nullptr, nullptr, nullptr, nullptr, nullptr, 768, 768, 768,
      512, 393216, 393216, 262144, scale);
  softmax_k<512><<<16384, 256, 0, stream>>>(attb);

  // TSA = att @ V  -> reduce only (B = batch-local Vt, ldb 512)
  gemm_f_k<3><<<dim3(6, 2, 32), blk512, 0, stream>>>(
      attb, Vt, nullptr, nullptr, nullptr, nullptr, colsum_tsa, bstat_tsa, 512,
      512, 512, 0, 262144, 393216, 0, 0.f);
  // FSA = V @ attN -> reduce only  (B rows = attNt rows g)
  gemm_f_k<3><<<dim3(6, 2, 32), blk512, 0, stream>>>(
      Vb, attNt, nullptr, nullptr, nullptr, nullptr, colsum_fsa, bstat_fsa, 768,
      768, 768, 0, 393216, 589824, 0, 0.f);

  // remaining gate-branch statistics
  col_stats_k<<<dim3(32, 3), blk, 0, stream>>>(tokb, Wfs, bfs, gate_t, gate_f,
                                               colsum_tok, colsumsq_tok, colsum_tsg);
  batch_stats_k<<<32, blk, 0, stream>>>(gate_t, rowsum, rowsumsq, gate_f,
                                        colsum_tok, colsumsq_tok, st4);

  pooled_k<<<32, 768, 0, stream>>>(colsum_tok, colsum_tsa, bstat_tsa, colsum_fsa,
                                   bstat_fsa, colsum_tgsa, bstat_tgsa, colsum_tsg,
                                   gate_f, st4, pooled);
  fnn1_k<<<dim3(6, 42), blk, 0, stream>>>(pooled, W1, tmp1);
  fnn2_k<<<24, blk, 0, stream>>>(tmp1, b1, W2, b2, out);
}

// Round 11
// 386.213 us; speedup vs baseline: 2.2290x; 1.0844x over previous
//
#include <hip/hip_runtime.h>
#include <cmath>

typedef unsigned short u16;
typedef __attribute__((ext_vector_type(4))) float f32x4;
typedef __attribute__((ext_vector_type(4))) unsigned int u32x4;
typedef __attribute__((ext_vector_type(8))) __bf16 bf16x8;

__device__ __forceinline__ u16 f2b(float f) {
  unsigned int u = __builtin_bit_cast(unsigned int, f);
  return (u16)((u + 0x7fffu + ((u >> 16) & 1u)) >> 16);  // RNE
}
__device__ __forceinline__ float b2f(u16 h) {
  unsigned int u = ((unsigned int)h) << 16;
  return __builtin_bit_cast(float, u);
}

__device__ __forceinline__ void glds16(const u16* g, u16* l) {
  __builtin_amdgcn_global_load_lds(
      (const __attribute__((address_space(1))) void*)g,
      (__attribute__((address_space(3))) void*)l, 16, 0, 0);
}

// ---------------------------------------------------------------------------
// Fast bf16-MFMA GEMM, 256x128 tile, BK=32, 512 threads (8 waves, 4x2).
// A: M x K row-major bf16 (lda), per-z stride sA; B: N x K row-major (ldb).
// global_load_lds w16, double-buffered, counted vmcnt(3), chunk swizzle on
// both global-src and ds_read sides. Bijective XCD remap (nwg % 8 == 0).
// Stores through L2 (no nontemporal - r7 lesson).
// EPI 0: fused QKV (N=2304): C row-major + C^T batch-local [z][768][512].
// EPI 1: TGSA reduce: sigmoid(acc+bias)*tokb -> colsum/bsum/bsumsq
// EPI 3: reduce-only: colsum[z,n], bsum[z], bsumsq[z]        (FSA)
// EPI 4: store E=exp(scale*acc) + column sum-of-exp partials (attN^T)
// EPI 5: store E=exp(scale*acc) + row sums (atomic)          (att scores)
// EPI 6: reduce with per-row scale 1/rs[row]                 (TSA)
// Softmax thus never takes its own pass: exp(x)/S folded into neighbors.
// Scores are ~N(0,1) so max-free exp is safe (exp(<=8) well in range).
// ---------------------------------------------------------------------------
template <int EPI>
__global__ __launch_bounds__(512) void gemm_f_k(
    const u16* __restrict__ Ap, const u16* __restrict__ Bp, u16* __restrict__ Cp,
    u16* __restrict__ CpT, const float* __restrict__ bias,
    const u16* __restrict__ tokp, float* __restrict__ colsum,
    float* __restrict__ bstat, const float* __restrict__ rs, int K, int lda,
    int ldb, int ldc, long sA, long sB, long sC, float scale) {
  __shared__ alignas(16) u16 Asm[2][8192];  // 256 rows x 32 u16, dbuf
  __shared__ alignas(16) u16 Bsm[2][4096];  // 128 rows x 32 u16, dbuf
  __shared__ float scol_s[128];
  __shared__ float scrow[256];
  __shared__ float sred[2];

  // bijective XCD-chunked remap (nwg % 8 == 0 for all our grids)
  const int gx = gridDim.x, gxy = gx * gridDim.y;
  const int nwg = gxy * gridDim.z;
  int orig = (blockIdx.z * gridDim.y + blockIdx.y) * gx + blockIdx.x;
  int gwi = (orig & 7) * (nwg >> 3) + (orig >> 3);
  const int z = gwi / gxy;
  int rem = gwi - z * gxy;
  const int ty = rem / gx, tx = rem - ty * gx;
  const int tileM = ty << 8, tileN = tx << 7;

  const u16* Abase = Ap + (size_t)z * sA;
  const u16* Bbase = Bp + (size_t)z * sB;

  const int tid = threadIdx.x;
  const int lane = tid & 63, w = tid >> 6;          // w in [0,8)
  const int wr = (w >> 1) << 6, wc = (w & 1) << 6;  // 4 row-waves x 2 col-waves
  const int fr = lane & 15, fg = lane >> 4;

  f32x4 acc[4][4];
#pragma unroll
  for (int i = 0; i < 4; ++i)
#pragma unroll
    for (int j = 0; j < 4; ++j) acc[i][j] = (f32x4){0.f, 0.f, 0.f, 0.f};

  // staging: wave w covers A rows [w*32,w*32+32) and B rows [w*16,w*16+16).
  const int sArow = (w << 5) + (lane >> 2);
  const int sBrow = (w << 4) + (lane >> 2);
  const int scol = (((lane & 3) ^ ((lane >> 3) & 3)) << 3);
  const u16* gA = Abase + (size_t)(tileM + sArow) * lda + scol;
  const u16* gB = Bbase + (size_t)(tileN + sBrow) * ldb + scol;
  const int ldsA = (w << 5) * 32;
  const int ldsB = (w << 4) * 32;

  auto STAGE = [&](int buf, int k0) {
    glds16(gA + k0, &Asm[buf][ldsA]);
    glds16(gA + (size_t)16 * lda + k0, &Asm[buf][ldsA + 512]);
    glds16(gB + k0, &Bsm[buf][ldsB]);
  };

  const int col_off = ((fg ^ ((fr >> 1) & 3)) << 3);

  const int nt = K >> 5;
  STAGE(0, 0);
  int cur = 0;
  for (int t = 0; t < nt; ++t) {
    if (t + 1 < nt) {
      STAGE(cur ^ 1, (t + 1) << 5);
      asm volatile("s_waitcnt vmcnt(3)" ::: "memory");
    } else {
      asm volatile("s_waitcnt vmcnt(0)" ::: "memory");
    }
    __builtin_amdgcn_s_barrier();
    asm volatile("" ::: "memory");
    const u16* Ab = Asm[cur];
    const u16* Bb = Bsm[cur];
    bf16x8 av[4], bw[4];
#pragma unroll
    for (int m = 0; m < 4; ++m)
      av[m] = *(const bf16x8*)&Ab[(wr + (m << 4) + fr) * 32 + col_off];
#pragma unroll
    for (int n = 0; n < 4; ++n)
      bw[n] = *(const bf16x8*)&Bb[(wc + (n << 4) + fr) * 32 + col_off];
#pragma unroll
    for (int m = 0; m < 4; ++m)
#pragma unroll
      for (int n = 0; n < 4; ++n)
        acc[m][n] =
            __builtin_amdgcn_mfma_f32_16x16x32_bf16(av[m], bw[n], acc[m][n], 0, 0, 0);
    asm volatile("" ::: "memory");
    __builtin_amdgcn_s_barrier();
    cur ^= 1;
  }

  // ---- epilogue ----
  if constexpr (EPI == 0) {
    const int cbuf = tileN / 768;
    const int nbase = tileN - cbuf * 768;
    u16* Cz = Cp + (size_t)cbuf * sC;
#pragma unroll
    for (int m = 0; m < 4; ++m) {
#pragma unroll
      for (int n = 0; n < 4; ++n) {
        const int gcol = tileN + wc + (n << 4) + fr;
        const int lcol = nbase + wc + (n << 4) + fr;
        const float bv2 = bias[gcol];
#pragma unroll
        for (int r = 0; r < 4; ++r) {
          const int grow = tileM + wr + (m << 4) + (fg << 2) + r;
          Cz[(size_t)grow * 768 + lcol] = f2b(acc[m][n][r] + bv2);
        }
      }
    }
    // transposed store: batch-local [z][768][512] (1KB column stride)
    u16* Ct = CpT + (size_t)cbuf * sC;
    const int zb = tileM >> 9;
    const int sbase = tileM & 511;
#pragma unroll
    for (int m = 0; m < 4; ++m) {
#pragma unroll
      for (int n = 0; n < 4; ++n) {
        const int gcol = tileN + wc + (n << 4) + fr;
        const int lcol = nbase + wc + (n << 4) + fr;
        const int srow0 = sbase + wr + (m << 4) + (fg << 2);
        union { u16 u[4]; unsigned long long q; } pk;
#pragma unroll
        for (int r = 0; r < 4; ++r) pk.u[r] = f2b(acc[m][n][r] + bias[gcol]);
        *(unsigned long long*)&Ct[((size_t)(zb * 768 + lcol) << 9) + srow0] = pk.q;
      }
    }
  } else if constexpr (EPI == 1) {
    // TGSA: v = sigmoid(acc + btg[n]) * tokb[m,n]
    if (tid < 128) scol_s[tid] = 0.f;
    if (tid == 0) { sred[0] = 0.f; sred[1] = 0.f; }
    __syncthreads();
    float ls = 0.f, lq = 0.f;
#pragma unroll
    for (int n = 0; n < 4; ++n) {
      float cpart = 0.f;
      const int gcol = tileN + wc + (n << 4) + fr;
      const float bv2 = bias[gcol];
#pragma unroll
      for (int m = 0; m < 4; ++m) {
#pragma unroll
        for (int r = 0; r < 4; ++r) {
          const int grow = tileM + wr + (m << 4) + (fg << 2) + r;
          float g = 1.f / (1.f + __expf(-(acc[m][n][r] + bv2)));
          float v = g * b2f(tokp[(size_t)grow * 768 + gcol]);
          cpart += v; ls += v; lq += v * v;
        }
      }
      atomicAdd(&scol_s[wc + (n << 4) + fr], cpart);
    }
    atomicAdd(&sred[0], ls);
    atomicAdd(&sred[1], lq);
    __syncthreads();
    const int b = tileM >> 9;
    if (tid < 128) atomicAdd(&colsum[(size_t)b * 768 + tileN + tid], scol_s[tid]);
    if (tid == 0) {
      atomicAdd(&bstat[b], sred[0]);
      atomicAdd(&bstat[32 + b], sred[1]);
    }
  } else if constexpr (EPI == 4) {
    // attN^T: store E = exp(scale*acc); column sum-of-exp partials
    u16* Cz = Cp + (size_t)z * sC;
    float lsum[4];
#pragma unroll
    for (int n = 0; n < 4; ++n) {
      const int gcol = tileN + wc + (n << 4) + fr;
      float s2 = 0.f;
#pragma unroll
      for (int m = 0; m < 4; ++m) {
#pragma unroll
        for (int r = 0; r < 4; ++r) {
          const int grow = tileM + wr + (m << 4) + (fg << 2) + r;
          float e = __expf(acc[m][n][r] * scale);
          Cz[(size_t)grow * ldc + gcol] = f2b(e);
          s2 += e;
        }
      }
      lsum[n] = s2;
    }
    float* red = (float*)&Asm[0][0];  // [16 slots][132] conflict-free
    const int slot = ((w >> 1) << 2) + fg;
    __syncthreads();
#pragma unroll
    for (int n = 0; n < 4; ++n)
      red[slot * 132 + wc + (n << 4) + fr] = lsum[n];
    __syncthreads();
    if (tid < 128) {
      float s2 = 0.f;
#pragma unroll
      for (int i = 0; i < 16; ++i) s2 += red[i * 132 + tid];
      const int ty3 = tileM >> 8;  // 0..2
      colsum[((size_t)z * 3 + ty3) * 768 + tileN + tid] = s2;
    }
  } else if constexpr (EPI == 5) {
    // att scores: store E = exp(scale*acc); per-row sums -> colsum (atomic)
    u16* Cz = Cp + (size_t)z * sC;
    if (tid < 256) scrow[tid] = 0.f;
    __syncthreads();
    float rpart[4][4];
#pragma unroll
    for (int m = 0; m < 4; ++m)
#pragma unroll
      for (int r = 0; r < 4; ++r) rpart[m][r] = 0.f;
#pragma unroll
    for (int n = 0; n < 4; ++n) {
      const int gcol = tileN + wc + (n << 4) + fr;
#pragma unroll
      for (int m = 0; m < 4; ++m) {
#pragma unroll
        for (int r = 0; r < 4; ++r) {
          const int grow = tileM + wr + (m << 4) + (fg << 2) + r;
          float e = __expf(acc[m][n][r] * scale);
          Cz[(size_t)grow * ldc + gcol] = f2b(e);
          rpart[m][r] += e;
        }
      }
    }
#pragma unroll
    for (int m = 0; m < 4; ++m) {
#pragma unroll
      for (int r = 0; r < 4; ++r) {
        float v = rpart[m][r];
        v += __shfl_xor(v, 1); v += __shfl_xor(v, 2);
        v += __shfl_xor(v, 4); v += __shfl_xor(v, 8);
        if (fr == 0) atomicAdd(&scrow[wr + (m << 4) + (fg << 2) + r], v);
      }
    }
    __syncthreads();
    if (tid < 256) atomicAdd(&colsum[(size_t)z * 512 + tileM + tid], scrow[tid]);
  } else if constexpr (EPI == 6) {
    // TSA reduce with per-row scale 1/rs[row]  (exact softmax*V)
    float isr[4][4];
#pragma unroll
    for (int m = 0; m < 4; ++m)
#pragma unroll
      for (int r = 0; r < 4; ++r)
        isr[m][r] =
            1.f / rs[(size_t)z * 512 + tileM + wr + (m << 4) + (fg << 2) + r];
    if (tid < 128) scol_s[tid] = 0.f;
    if (tid == 0) { sred[0] = 0.f; sred[1] = 0.f; }
    __syncthreads();
    float ls = 0.f, lq = 0.f;
#pragma unroll
    for (int n = 0; n < 4; ++n) {
      float cpart = 0.f;
#pragma unroll
      for (int m = 0; m < 4; ++m) {
#pragma unroll
        for (int r = 0; r < 4; ++r) {
          float v = acc[m][n][r] * isr[m][r];
          cpart += v; ls += v; lq += v * v;
        }
      }
      atomicAdd(&scol_s[wc + (n << 4) + fr], cpart);
    }
    atomicAdd(&sred[0], ls);
    atomicAdd(&sred[1], lq);
    __syncthreads();
    if (tid < 128) atomicAdd(&colsum[(size_t)z * 768 + tileN + tid], scol_s[tid]);
    if (tid == 0) {
      atomicAdd(&bstat[z], sred[0]);
      atomicAdd(&bstat[32 + z], sred[1]);
    }
  } else {
    if (tid < 128) scol_s[tid] = 0.f;
    if (tid == 0) { sred[0] = 0.f; sred[1] = 0.f; }
    __syncthreads();
    float ls = 0.f, lq = 0.f;
#pragma unroll
    for (int n = 0; n < 4; ++n) {
      float cpart = 0.f;
#pragma unroll
      for (int m = 0; m < 4; ++m) {
#pragma unroll
        for (int r = 0; r < 4; ++r) {
          float v = acc[m][n][r];
          cpart += v; ls += v; lq += v * v;
        }
      }
      atomicAdd(&scol_s[wc + (n << 4) + fr], cpart);
    }
    atomicAdd(&sred[0], ls);
    atomicAdd(&sred[1], lq);
    __syncthreads();
    if (tid < 128) atomicAdd(&colsum[(size_t)z * 768 + tileN + tid], scol_s[tid]);
    if (tid == 0) {
      atomicAdd(&bstat[z], sred[0]);
      atomicAdd(&bstat[32 + z], sred[1]);
    }
  }
}

// fused: tokens f32 -> tokb bf16 + per-row gate_t/rowsum/rowsumsq. 1 wave/row.
__global__ __launch_bounds__(256) void cvt_row_k(
    const float* __restrict__ tok, u16* __restrict__ tokb,
    const float* __restrict__ Wts, const float* __restrict__ bts,
    float* __restrict__ gate_t, float* __restrict__ rowsum,
    float* __restrict__ rowsumsq) {
  const int w = threadIdx.x >> 6, lane = threadIdx.x & 63;
  const int row = blockIdx.x * 4 + w;
  const float* p = tok + (size_t)row * 768;
  u16* q = tokb + (size_t)row * 768;
  float s = 0.f, sq = 0.f, g = 0.f;
#pragma unroll
  for (int i = 0; i < 3; ++i) {
    const int idx = (i * 64 + lane) << 2;
    f32x4 v = *(const f32x4*)(p + idx);
    f32x4 wv = *(const f32x4*)(Wts + idx);
    union { u16 u[4]; unsigned long long q8; } pk;
#pragma unroll
    for (int j = 0; j < 4; ++j) {
      s += v[j]; sq += v[j] * v[j]; g += v[j] * wv[j];
      pk.u[j] = f2b(v[j]);
    }
    *(unsigned long long*)(q + idx) = pk.q8;
  }
#pragma unroll
  for (int o = 32; o > 0; o >>= 1) {
    s += __shfl_xor(s, o); sq += __shfl_xor(sq, o); g += __shfl_xor(g, o);
  }
  if (lane == 0) {
    gate_t[row] = fmaxf(g + bts[0], 0.f);
    rowsum[row] = s;
    rowsumsq[row] = sq;
  }
}

// 4x W [768][768] f32 -> WT bf16 transposed (z selects source)
__global__ __launch_bounds__(256) void transpose_w4_k(
    const float* __restrict__ W0, const float* __restrict__ W1,
    const float* __restrict__ W2, const float* __restrict__ W3,
    u16* __restrict__ WT) {
  const float* W = blockIdx.z == 0 ? W0 : blockIdx.z == 1 ? W1
                   : blockIdx.z == 2 ? W2 : W3;
  u16* dst = WT + (size_t)blockIdx.z * 589824;
  __shared__ float t[64][65];
  const int r0 = blockIdx.y << 6, c0 = blockIdx.x << 6;
  for (int i = threadIdx.x; i < 4096; i += 256) {
    int r = i >> 6, c = i & 63;
    t[r][c] = W[(size_t)(r0 + r) * 768 + c0 + c];
  }
  __syncthreads();
  for (int i = threadIdx.x; i < 4096; i += 256) {
    int rr = i >> 6, cc = i & 63;
    dst[(size_t)(c0 + rr) * 768 + r0 + cc] = f2b(t[cc][rr]);
  }
}

// V2[z][s][h] = Vb[z][s][h] / S_col[z][h], S from attNt column partials.
__global__ __launch_bounds__(256) void v2scale_k(const u16* __restrict__ Vb,
                                                 const float* __restrict__ psum,
                                                 u16* __restrict__ V2) {
  __shared__ float inv[768];
  const int z = blockIdx.x, sb = blockIdx.y;
  const float* pz = psum + (size_t)z * 2304;
  for (int h = threadIdx.x; h < 768; h += 256)
    inv[h] = 1.f / (pz[h] + pz[h + 768] + pz[h + 1536]);
  __syncthreads();
  const size_t base = (size_t)z * 393216 + (size_t)sb * 64 * 768;
  for (int i = 0; i < 24; ++i) {
    const int u = i * 256 + threadIdx.x;
    const int row = u / 96, seg = (u - row * 96) * 8;
    const size_t idx = base + (size_t)row * 768 + seg;
    union { u32x4 q; u16 us[8]; } in, ot;
    in.q = *(const u32x4*)&Vb[idx];
#pragma unroll
    for (int j = 0; j < 8; ++j) ot.us[j] = f2b(b2f(in.us[j]) * inv[seg + j]);
    *(u32x4*)&V2[idx] = ot.q;
  }
}

// per-column stats from tokb: gate_f, colsum_tok, colsumsq_tok, colsum_tsgsa.
__global__ __launch_bounds__(256) void col_stats_k(
    const u16* __restrict__ tokb, const float* __restrict__ Wfs,
    const float* __restrict__ bfs, const float* __restrict__ gate_t,
    float* __restrict__ gate_f, float* __restrict__ colsum_tok,
    float* __restrict__ colsumsq_tok, float* __restrict__ colsum_tsg) {
  const int b = blockIdx.x, h = blockIdx.y * 256 + threadIdx.x;
  const u16* p = tokb + (size_t)b * 512 * 768 + h;
  const float* gt = gate_t + b * 512;
  float cs = 0.f, cq = 0.f, gf = 0.f, tg = 0.f;
#pragma unroll 4
  for (int s = 0; s < 512; ++s) {
    float t = b2f(p[(size_t)s * 768]);
    cs += t; cq += t * t; gf += t * Wfs[s]; tg += t * gt[s];
  }
  const int idx = b * 768 + h;
  gate_f[idx] = fmaxf(gf + bfs[0], 0.f);
  colsum_tok[idx] = cs;
  colsumsq_tok[idx] = cq;
  colsum_tsg[idx] = tg;
}

// per-batch scalar stats for TSGSA and FSGSA. st: [tsg_s|tsg_q|fsg_s|fsg_q]x32
__global__ __launch_bounds__(256) void batch_stats_k(
    const float* __restrict__ gate_t, const float* __restrict__ rowsum,
    const float* __restrict__ rowsumsq, const float* __restrict__ gate_f,
    const float* __restrict__ colsum_tok, const float* __restrict__ colsumsq_tok,
    float* __restrict__ st) {
  __shared__ float red[4][256];
  const int b = blockIdx.x, tid = threadIdx.x;
  float ts = 0.f, tq = 0.f, fs = 0.f, fq = 0.f;
  for (int s = tid; s < 512; s += 256) {
    float g = gate_t[b * 512 + s];
    ts += g * rowsum[b * 512 + s];
    tq += g * g * rowsumsq[b * 512 + s];
  }
  for (int h = tid; h < 768; h += 256) {
    float g = gate_f[b * 768 + h];
    fs += g * colsum_tok[b * 768 + h];
    fq += g * g * colsumsq_tok[b * 768 + h];
  }
  red[0][tid] = ts; red[1][tid] = tq; red[2][tid] = fs; red[3][tid] = fq;
  __syncthreads();
  for (int o = 128; o > 0; o >>= 1) {
    if (tid < o) {
      red[0][tid] += red[0][tid + o];
      red[1][tid] += red[1][tid + o];
      red[2][tid] += red[2][tid + o];
      red[3][tid] += red[3][tid + o];
    }
    __syncthreads();
  }
  if (tid == 0) {
    st[b] = red[0][0]; st[32 + b] = red[1][0];
    st[64 + b] = red[2][0]; st[96 + b] = red[3][0];
  }
}

// build pooled [B, 7*768] from column sums + batch stats
__global__ __launch_bounds__(768) void pooled_k(
    const float* __restrict__ colsum_tok, const float* __restrict__ colsum_tsa,
    const float* __restrict__ bstat_tsa, const float* __restrict__ colsum_fsa,
    const float* __restrict__ bstat_fsa, const float* __restrict__ colsum_tgsa,
    const float* __restrict__ bstat_tgsa, const float* __restrict__ colsum_tsg,
    const float* __restrict__ gate_f, const float* __restrict__ st,
    float* __restrict__ pooled) {
  const int b = blockIdx.x, h = threadIdx.x;
  const float invS = 1.f / 512.f, invN = 1.f / (512.f * 768.f);
  const int i = b * 768 + h;
  float* pr = pooled + (size_t)b * 5376;
  pr[h] = colsum_tok[i] * invS;
  auto lnslot = [&](int slot, float cs, float bs, float bq) {
    float m = bs * invN;
    float var = bq * invN - m * m;
    pr[slot * 768 + h] = (cs * invS - m) * rsqrtf(var + 1e-8f);
  };
  lnslot(1, colsum_tsa[i], bstat_tsa[b], bstat_tsa[32 + b]);
  lnslot(2, colsum_fsa[i], bstat_fsa[b], bstat_fsa[32 + b]);
  lnslot(3, colsum_tgsa[i], bstat_tgsa[b], bstat_tgsa[32 + b]);
  const float fsg_cs = gate_f[i] * colsum_tok[i];
  lnslot(4, fsg_cs, st[64 + b], st[96 + b]);
  lnslot(5, colsum_tsg[i], st[b], st[32 + b]);
  lnslot(6, fsg_cs, st[64 + b], st[96 + b]);
}

// tmp1 += pooled-slice . W1-slice.  grid (6 colchunks, 42 kchunks), 256 thr.
__global__ __launch_bounds__(256) void fnn1_k(const float* __restrict__ pooled,
                                              const float* __restrict__ W1,
                                              float* __restrict__ tmp1) {
  __shared__ float sp[128][36];
  const int c0 = blockIdx.x << 7, k0 = blockIdx.y << 7;
  const int tid = threadIdx.x;
  for (int i = tid; i < 4096; i += 256) {
    int b = i >> 7, j = i & 127;
    sp[j][b] = pooled[(size_t)b * 5376 + k0 + j];
  }
  __syncthreads();
  const int c = c0 + (tid & 127);
  const int u = (tid >> 7) << 4;
  float acc[16];
#pragma unroll
  for (int t = 0; t < 16; ++t) acc[t] = 0.f;
#pragma unroll 4
  for (int j = 0; j < 128; ++j) {
    float w = W1[(size_t)(k0 + j) * 768 + c];
    const f32x4* row = (const f32x4*)&sp[j][u];
#pragma unroll
    for (int t4 = 0; t4 < 4; ++t4) {
      f32x4 v = row[t4];
#pragma unroll
      for (int r = 0; r < 4; ++r) acc[t4 * 4 + r] += v[r] * w;
    }
  }
#pragma unroll
  for (int t = 0; t < 16; ++t) atomicAdd(&tmp1[(u + t) * 768 + c], acc[t]);
}

// out[b,c] = sum_k (tmp1[b,k]+b1[k]) * W2[k,c] + b2[c].  One wave per output.
__global__ __launch_bounds__(256) void fnn2_k(const float* __restrict__ tmp1,
                                              const float* __restrict__ b1,
                                              const float* __restrict__ W2,
                                              const float* __restrict__ b2,
                                              float* __restrict__ out) {
  const int gw = blockIdx.x * 4 + (threadIdx.x >> 6);
  const int lane = threadIdx.x & 63;
  const int b = gw / 3, c = gw % 3;
  float a = 0.f;
#pragma unroll
  for (int i = 0; i < 12; ++i) {
    int k = lane + i * 64;
    a += (tmp1[b * 768 + k] + b1[k]) * W2[k * 3 + c];
  }
#pragma unroll
  for (int o = 32; o > 0; o >>= 1) a += __shfl_xor(a, o);
  if (lane == 0) out[b * 3 + c] = a + b2[c];
}

extern "C" void kernel_launch(void* const* d_in, const int* in_sizes, int n_in,
                              void* d_out, int out_size, void* d_ws, size_t ws_size,
                              hipStream_t stream) {
  const float* tokens = (const float*)d_in[0];
  const float* Wq = (const float*)d_in[1];
  const float* bq = (const float*)d_in[2];
  const float* Wk = (const float*)d_in[3];
  const float* bk = (const float*)d_in[4];
  const float* Wv = (const float*)d_in[5];
  const float* bv = (const float*)d_in[6];
  const float* Wts = (const float*)d_in[7];
  const float* bts = (const float*)d_in[8];
  const float* Wfs = (const float*)d_in[9];
  const float* bfs = (const float*)d_in[10];
  const float* Wtg = (const float*)d_in[11];
  const float* btg = (const float*)d_in[12];
  const float* W1 = (const float*)d_in[13];
  const float* b1 = (const float*)d_in[14];
  const float* W2 = (const float*)d_in[15];
  const float* b2 = (const float*)d_in[16];
  float* out = (float*)d_out;

  char* ws = (char*)d_ws;
  size_t off = 0;
  auto take = [&](size_t bytes) -> char* {
    char* p = ws + off;
    off += (bytes + 255) & ~(size_t)255;
    return p;
  };
  u16* tokb = (u16*)take((size_t)16384 * 768 * 2);
  u16* WqT = (u16*)take((size_t)768 * 768 * 2);  // WqT..WtgT contiguous
  u16* WkT = (u16*)take((size_t)768 * 768 * 2);
  u16* WvT = (u16*)take((size_t)768 * 768 * 2);
  u16* WtgT = (u16*)take((size_t)768 * 768 * 2);
  u16* Qb = (u16*)take((size_t)16384 * 768 * 2);  // Qb/Kb/Vb contiguous
  u16* Kb = (u16*)take((size_t)16384 * 768 * 2);
  u16* Vb = (u16*)take((size_t)16384 * 768 * 2);
  u16* Qt = (u16*)take((size_t)32 * 768 * 512 * 2);  // batch-local [z][768][512]
  u16* Kt = (u16*)take((size_t)32 * 768 * 512 * 2);
  u16* Vt = (u16*)take((size_t)32 * 768 * 512 * 2);
  u16* attb = (u16*)take((size_t)32 * 512 * 512 * 2);
  u16* attNt = (u16*)take((size_t)32 * 768 * 768 * 2);  // E = exp scores
  float* bias3 = (float*)take(2304 * 4);
  float* psum = (float*)take((size_t)32 * 3 * 768 * 4);
  u16* V2 = Qt;  // Qt dead after attNt GEMM; V2 = Vb / S_col (same 25.2MB)
  // --- zeroed (atomic-accumulated) region: keep contiguous ---
  char* zbase = ws + off;
  float* colsum_tsa = (float*)take(24576 * 4);
  float* colsum_fsa = (float*)take(24576 * 4);
  float* colsum_tgsa = (float*)take(24576 * 4);
  float* bstat_tsa = (float*)take(64 * 4);
  float* bstat_fsa = (float*)take(64 * 4);
  float* bstat_tgsa = (float*)take(64 * 4);
  float* rowsumE = (float*)take((size_t)32 * 512 * 4);
  float* tmp1 = (float*)take((size_t)32 * 768 * 4);
  size_t zbytes = (size_t)((ws + off) - zbase);
  // --- fully-overwritten buffers ---
  float* colsum_tsg = (float*)take(24576 * 4);
  float* gate_t = (float*)take(16384 * 4);
  float* rowsum = (float*)take(16384 * 4);
  float* rowsumsq = (float*)take(16384 * 4);
  float* gate_f = (float*)take(24576 * 4);
  float* colsum_tok = (float*)take(24576 * 4);
  float* colsumsq_tok = (float*)take(24576 * 4);
  float* st4 = (float*)take(128 * 4);
  float* pooled = (float*)take((size_t)32 * 5376 * 4);

  hipMemsetAsync(zbase, 0, zbytes, stream);
  hipMemcpyAsync(bias3, bq, 768 * 4, hipMemcpyDeviceToDevice, stream);
  hipMemcpyAsync(bias3 + 768, bk, 768 * 4, hipMemcpyDeviceToDevice, stream);
  hipMemcpyAsync(bias3 + 1536, bv, 768 * 4, hipMemcpyDeviceToDevice, stream);

  const float scale = 1.0f / sqrtf(768.0f);
  const dim3 blk(256);
  const dim3 blk512(512);

  // prep: tokens->bf16 + row stats (fused); weights->transposed bf16
  cvt_row_k<<<4096, blk, 0, stream>>>(tokens, tokb, Wts, bts, gate_t, rowsum,
                                      rowsumsq);
  transpose_w4_k<<<dim3(12, 12, 4), blk, 0, stream>>>(Wq, Wk, Wv, Wtg, WqT);

  // fused Q|K|V projection: N=2304, BM=256, batch-local transposed outputs
  gemm_f_k<0><<<dim3(18, 64, 1), blk512, 0, stream>>>(
      tokb, WqT, Qb, Qt, bias3, nullptr, nullptr, nullptr, nullptr, 768, 768,
      768, 768, 0, 0, 12582912, 0.f);
  // TGSA (gated reduce), reads tokb
  gemm_f_k<1><<<dim3(6, 64, 1), blk512, 0, stream>>>(
      tokb, WtgT, nullptr, nullptr, btg, tokb, colsum_tgsa, bstat_tgsa, nullptr,
      768, 768, 768, 0, 0, 0, 0, 0.f);

  // attN^T exp-scores + column sum-of-exp partials
  gemm_f_k<4><<<dim3(6, 3, 32), blk512, 0, stream>>>(
      Kt, Qt, attNt, nullptr, nullptr, nullptr, psum, nullptr, nullptr, 512,
      512, 512, 768, 393216, 393216, 589824, scale);
  // V2 = Vb / S_col  (folds the feature-softmax denominator into V)
  v2scale_k<<<dim3(32, 8), blk, 0, stream>>>(Vb, psum, V2);

  // token attention exp-scores + row sums (softmax pass eliminated)
  gemm_f_k<5><<<dim3(4, 2, 32), blk512, 0, stream>>>(
      Qb, Kb, attb, nullptr, nullptr, nullptr, rowsumE, nullptr, nullptr, 768,
      768, 768, 512, 393216, 393216, 262144, scale);

  // TSA = (E/S_row) @ V -> reduce with per-row scale
  gemm_f_k<6><<<dim3(6, 2, 32), blk512, 0, stream>>>(
      attb, Vt, nullptr, nullptr, nullptr, nullptr, colsum_tsa, bstat_tsa,
      rowsumE, 512, 512, 512, 0, 262144, 393216, 0, 0.f);
  // FSA = (V/S_col) @ E -> plain reduce
  gemm_f_k<3><<<dim3(6, 2, 32), blk512, 0, stream>>>(
      V2, attNt, nullptr, nullptr, nullptr, nullptr, colsum_fsa, bstat_fsa,
      nullptr, 768, 768, 768, 0, 393216, 589824, 0, 0.f);

  // remaining gate-branch statistics
  col_stats_k<<<dim3(32, 3), blk, 0, stream>>>(tokb, Wfs, bfs, gate_t, gate_f,
                                               colsum_tok, colsumsq_tok, colsum_tsg);
  batch_stats_k<<<32, blk, 0, stream>>>(gate_t, rowsum, rowsumsq, gate_f,
                                        colsum_tok, colsumsq_tok, st4);

  pooled_k<<<32, 768, 0, stream>>>(colsum_tok, colsum_tsa, bstat_tsa, colsum_fsa,
                                   bstat_fsa, colsum_tgsa, bstat_tgsa, colsum_tsg,
                                   gate_f, st4, pooled);
  fnn1_k<<<dim3(6, 42), blk, 0, stream>>>(pooled, W1, tmp1);
  fnn2_k<<<24, blk, 0, stream>>>(tmp1, b1, W2, b2, out);
}